// Round 15
// baseline (378.514 us; speedup 1.0000x reference)
//
#include <hip/hip_runtime.h>
#include <math.h>

#define NA 2048          // atoms
#define KN 24            // neighbors per atom
#define NE (NA*KN)       // edges = 49152
#define NDIM 128         // node dim
#define EDIM 64          // rbf dim
#define HDIM 256         // hidden dim
#define NLAYER 4
#define MAXDEG 256       // cap on in-degree for CSR
#define EB 64            // edges per block in edge_fused

typedef __attribute__((ext_vector_type(8))) short bf16x8;
typedef __attribute__((ext_vector_type(4))) float f32x4;

// fast silu: x * rcp(1+exp(-x)). 1-ulp transcendental error, invisible under bf16 quant.
__device__ __forceinline__ float siluf(float x) {
    return __fdividef(x, 1.0f + __expf(-x));
}
__device__ __forceinline__ ushort f2b(float x) {  // RNE float->bf16
    unsigned u = __float_as_uint(x);
    return (ushort)((u + 0x7fffu + ((u >> 16) & 1u)) >> 16);
}
__device__ __forceinline__ float b2f(ushort h) { return __uint_as_float(((unsigned)h) << 16); }

// async global->LDS, 16B per lane. LDS dest = wave-uniform base + lane*16 (linear).
__device__ __forceinline__ void gl_lds(const void* g, void* lds) {
    __builtin_amdgcn_global_load_lds(
        (const __attribute__((address_space(1))) unsigned int*)g,
        (__attribute__((address_space(3))) unsigned int*)lds, 16, 0, 0);
}

struct Lat { float lx, xy, xz, ly, yz, lz; };

__device__ __forceinline__ Lat make_lattice(const float* lengths, const float* angles) {
    const float deg = 0.017453292519943295f;
    float a = lengths[0], b = lengths[1], c = lengths[2];
    float al = angles[0]*deg, be = angles[1]*deg, ga = angles[2]*deg;
    Lat L;
    L.lx = a;
    L.xy = b * cosf(ga);
    L.xz = c * cosf(be);
    L.ly = b * sinf(ga);
    L.yz = (b*c*cosf(al) - L.xy*L.xz) / L.ly;
    L.lz = sqrtf(c*c - L.xz*L.xz - L.yz*L.yz);
    return L;
}

// writes AoS cart + SoA cx/cy/cz; also zeroes ccnt (used by knn's fused scatter)
__global__ void setup_kernel(const float* __restrict__ frac, const float* __restrict__ lengths,
                             const float* __restrict__ angles, float* __restrict__ cart,
                             float* __restrict__ cxg, float* __restrict__ cyg,
                             float* __restrict__ czg, float* __restrict__ sv,
                             int* __restrict__ ccnt) {
    int i = blockIdx.x*blockDim.x + threadIdx.x;
    Lat L = make_lattice(lengths, angles);
    if (i < NA) {
        float f0 = frac[i*3], f1 = frac[i*3+1], f2 = frac[i*3+2];
        float x = f0*L.lx + f1*L.xy + f2*L.xz;
        float y = f1*L.ly + f2*L.yz;
        float z = f2*L.lz;
        cart[i*3+0] = x; cart[i*3+1] = y; cart[i*3+2] = z;
        cxg[i] = x; cyg[i] = y; czg[i] = z;
        ccnt[i] = 0;
    }
    if (i < 27) {
        float s0 = (float)(i/9 - 1), s1 = (float)((i/3)%3 - 1), s2 = (float)(i%3 - 1);
        sv[i*3+0] = s0*L.lx + s1*L.xy + s2*L.xz;
        sv[i*3+1] = s1*L.ly + s2*L.yz;
        sv[i*3+2] = s2*L.lz;
    }
}

// Per-atom top-24 + fused RBF + fused CSR scatter. One 64-lane wave per atom.
__global__ __launch_bounds__(64) void knn_kernel(
        const float* __restrict__ cxg, const float* __restrict__ cyg,
        const float* __restrict__ czg, const float* __restrict__ lengths,
        const float* __restrict__ angles, const float* __restrict__ sv,
        int* __restrict__ dstl, ushort* __restrict__ rbf16,
        int* __restrict__ ccnt, int* __restrict__ cedg) {
    __shared__ float sd2L[16][64];
    __shared__ int   sfL[16][64];
    const int lane = threadIdx.x;
    const int i = blockIdx.x;
    Lat L = make_lattice(lengths, angles);
    const float deg = 0.017453292519943295f;
    const bool ortho = fabsf(cosf(angles[0]*deg)) < 1e-6f &&
                       fabsf(cosf(angles[1]*deg)) < 1e-6f &&
                       fabsf(cosf(angles[2]*deg)) < 1e-6f;
    const float cx = cxg[i], cy = cyg[i], cz = czg[i];
    const float invlx = 1.0f/L.lx, invly = 1.0f/L.ly, invlz = 1.0f/L.lz;
    float R = 2.8f;
    int mycnt = 0, cnt = 0;
    bool flatm = false;
    for (int attempt = 0; attempt < 8; ++attempt) {
        const float R2 = R*R;
        mycnt = 0;
        flatm = !ortho || (attempt == 7);
        if (!flatm) {
#pragma unroll 2
            for (int j0 = 0; j0 < NA; j0 += 64) {
                const int j = j0 + lane;
                const float dx = cxg[j] - cx, dy = cyg[j] - cy, dz = czg[j] - cz;
                const float kx = rintf(dx*invlx), ky = rintf(dy*invly), kz = rintf(dz*invlz);
                const float ex = dx - (kx*L.lx + ky*L.xy + kz*L.xz);
                const float ey = dy - (ky*L.ly + kz*L.yz);
                const float ez = dz - kz*L.lz;
                const float d2 = fmaf(ex,ex,fmaf(ey,ey,ez*ez));
                if (d2 < R2 && d2 > 1e-4f) {
                    const int s = (1-(int)kx)*9 + (1-(int)ky)*3 + (1-(int)kz);
                    if (mycnt < 16) { sd2L[mycnt][lane] = d2; sfL[mycnt][lane] = (s<<11) + j; }
                    ++mycnt;
                }
            }
            if (__ballot(mycnt > 16)) {
                flatm = true;
            } else {
                int tot = mycnt;
                for (int off = 32; off > 0; off >>= 1) tot += __shfl_xor(tot, off, 64);
                cnt = tot;
            }
        }
        if (flatm) {
            cnt = 0;
            for (int s = 0; s < 27; ++s) {
                const float svx = sv[s*3], svy = sv[s*3+1], svz = sv[s*3+2];
                for (int j0 = 0; j0 < NA; j0 += 64) {
                    const int j = j0 + lane;
                    const float ex = cxg[j] + svx - cx;
                    const float ey = cyg[j] + svy - cy;
                    const float ez = czg[j] + svz - cz;
                    const float d2 = fmaf(ex,ex,fmaf(ey,ey,ez*ez));
                    const bool hit = (d2 < R2) && (d2 > 1e-4f);
                    const unsigned long long m = __ballot(hit);
                    const int rank = __popcll(m & ((1ull<<lane)-1ull));
                    const int slot = cnt + rank;
                    if (hit && slot < 1024) { sd2L[slot>>6][slot&63] = d2; sfL[slot>>6][slot&63] = (s<<11)+j; }
                    cnt += __popcll(m);
                }
            }
            cnt = min(cnt, 1024);
        }
        if (cnt >= KN) break;
        R = fminf(R*1.6f, flatm ? 8.0f : 5.9f);
    }
    int vq;
    if (flatm) vq = (lane < cnt) ? min(16, ((cnt - 1 - lane) >> 6) + 1) : 0;
    else       vq = mycnt;
    unsigned long long key[16];
#pragma unroll
    for (int q = 0; q < 16; ++q) {
        const float d2v = sd2L[q][lane];
        const int fl = sfL[q][lane];
        const unsigned long long kk = ((unsigned long long)__float_as_uint(d2v) << 20)
                                    | ((unsigned long long)(unsigned)fl << 4) | (unsigned)q;
        key[q] = (q < vq) ? kk : ~0ull;
    }
    float der[KN];
    for (int k = 0; k < KN; ++k) {
        unsigned long long lm = key[0];
#pragma unroll
        for (int q = 1; q < 16; ++q) lm = key[q] < lm ? key[q] : lm;
        for (int off = 32; off > 0; off >>= 1) {
            unsigned long long o = __shfl_xor(lm, off, 64);
            lm = o < lm ? o : lm;
        }
        der[k] = sqrtf(__uint_as_float((unsigned)(lm >> 20)));
        if (lane == 0) {
            const int jn = (int)((lm >> 4) & 2047u);
            dstl[i*KN + k] = jn;
            const int slot = atomicAdd(&ccnt[jn], 1);
            if (slot < MAXDEG) cedg[(size_t)jn*MAXDEG + slot] = i*KN + k;
        }
#pragma unroll
        for (int q = 0; q < 16; ++q) if (key[q] == lm) key[q] = ~0ull;
    }
    const float center = (8.0f/63.0f) * (float)lane;
    for (int k = 0; k < KN; ++k) {
        const float d = der[k];
        const float diff = d - center;
        const float g = __expf(diff*diff * -32.0f);
        const float cv = 0.5f * (__cosf(d * (float)(M_PI/8.0)) + 1.0f);
        rbf16[(size_t)(i*KN + k)*EDIM + lane] = f2b(g * cv);
    }
}

// one wave per node: 64-lane bitonic sort (ascending), serial fallback for cnt>64
__global__ void csort_kernel(const int* __restrict__ ccnt, int* __restrict__ cedg) {
    const int j = blockIdx.x*4 + (threadIdx.x >> 6);
    const int lane = threadIdx.x & 63;
    const int cnt = min(ccnt[j], MAXDEG);
    if (cnt <= 64) {
        int v = (lane < cnt) ? cedg[(size_t)j*MAXDEG + lane] : 0x7FFFFFFF;
#pragma unroll
        for (int k = 2; k <= 64; k <<= 1) {
#pragma unroll
            for (int s = k >> 1; s > 0; s >>= 1) {
                int o = __shfl_xor(v, s, 64);
                const bool up = ((lane & k) == 0);
                const bool lowhalf = ((lane & s) == 0);
                v = ((lowhalf == up) ? min(v, o) : max(v, o));
            }
        }
        if (lane < cnt) cedg[(size_t)j*MAXDEG + lane] = v;
    } else if (lane == 0) {
        int* L = cedg + (size_t)j*MAXDEG;
        for (int a = 1; a < cnt; ++a) {
            int v = L[a]; int b = a - 1;
            while (b >= 0 && L[b] > v) { L[b+1] = L[b]; --b; }
            L[b+1] = v;
        }
    }
}

__global__ void nf_init_kernel(const int* __restrict__ atom_types, const float* __restrict__ ts,
                               const float* __restrict__ emb, const float* __restrict__ tW,
                               const float* __restrict__ tb, float* __restrict__ nf,
                               ushort* __restrict__ nf16) {
    int i = blockIdx.x, c = threadIdx.x;  // 128 threads
    float acc = emb[atom_types[i]*NDIM + c] + tb[c];
    for (int kk = 0; kk < 128; ++kk) acc += ts[i*128 + kk] * tW[kk*NDIM + c];
    nf[i*NDIM + c] = acc;
    nf16[i*NDIM + c] = f2b(acc);
}

// LDS-tiled transpose+convert: Wt[l][n][k] = bf16(W[l][k][n]). 64x64 tiles.
__global__ void wprep_all(const float* __restrict__ eW1, const float* __restrict__ eW2,
                          const float* __restrict__ cW1, const float* __restrict__ nW1,
                          const float* __restrict__ nW2,
                          ushort* __restrict__ eW1t, ushort* __restrict__ eW2t,
                          ushort* __restrict__ cW1t, ushort* __restrict__ nW1t,
                          ushort* __restrict__ nW2t) {
    __shared__ float tile[64][65];
    const int b = blockIdx.x;
    const float* W; ushort* Wt; int Kk, Nn, rel;
    if (b < 80)       { W = eW1; Wt = eW1t; Kk = 320; Nn = 256; rel = b; }
    else if (b < 144) { W = eW2; Wt = eW2t; Kk = 256; Nn = 256; rel = b - 80; }
    else if (b < 176) { W = cW1; Wt = cW1t; Kk = 256; Nn = 128; rel = b - 144; }
    else if (b < 272) { W = nW1; Wt = nW1t; Kk = 384; Nn = 256; rel = b - 176; }
    else              { W = nW2; Wt = nW2t; Kk = 256; Nn = 128; rel = b - 272; }
    const int kt = Kk >> 6, nt = Nn >> 6, per = kt*nt;
    const int l = rel / per, r2 = rel - l*per;
    const int k0 = (r2 / nt) * 64, n0 = (r2 - (r2/nt)*nt) * 64;
    const float* Wl = W + (size_t)l*Kk*Nn;
    ushort* Wtl = Wt + (size_t)l*Kk*Nn;
    const int tr = threadIdx.x >> 6, tc = threadIdx.x & 63;
#pragma unroll
    for (int q = 0; q < 16; ++q) {
        const int k = q*4 + tr;
        tile[k][tc] = Wl[(size_t)(k0 + k)*Nn + n0 + tc];
    }
    __syncthreads();
#pragma unroll
    for (int q = 0; q < 16; ++q) {
        const int n = q*4 + tr;
        Wtl[(size_t)(n0 + n)*Kk + k0 + tc] = f2b(tile[tc][n]);
    }
}

// Fused edge chain: h1 -> msg -> wv. 64 edges/block, 256 threads (4 waves, 2x2).
// R15: SINGLE-BUFFERED weight staging -> LDS 49920 B -> 3 blocks/CU; grid 768 = one
// co-resident round (12 waves/CU TLP covers the drain; R5 showed dbuf was neutral).
// Hs (h1/msg tile, 64x256 bf16) swizzle: byte = row*512 + ((col*2) ^ ((row&7)<<4)).
__global__ __launch_bounds__(256) void edge_fused(
        const ushort* __restrict__ nf16, const int* __restrict__ dstl,
        const ushort* __restrict__ rbf16,
        const ushort* __restrict__ eW1t,   // [256][320]
        const ushort* __restrict__ eW2t,   // [256][256]
        const ushort* __restrict__ cW1t,   // [128][256]
        const float* __restrict__ eb1, const float* __restrict__ eb2,
        const float* __restrict__ cb1, const float* __restrict__ cW2v,
        const float* __restrict__ cb2v,
        ushort* __restrict__ msg16, float* __restrict__ wvout) {
    __shared__ alignas(16) char R0[32768];   // {As 4K @0 | Bs 16K @8192} -> overlay Hs 32K
    __shared__ alignas(16) char R1[16384];   // B2 16K -> overlay Cs 8K
    __shared__ int sdst[64];
    __shared__ float wred[2][64];
    ushort* As = (ushort*)R0;                // [64][32]
    ushort* Bs = (ushort*)(R0 + 8192);       // [256][32]
    ushort* B2 = (ushort*)R1;                // [256][32]
    ushort* Cs = (ushort*)R1;                // [128][32]

    const int t = threadIdx.x, wave = t >> 6, lane = t & 63;
    const int row0 = blockIdx.x*EB;
    if (t < EB) sdst[t] = dstl[row0 + t];
    __syncthreads();
    const int wr = (wave >> 1)*32;           // row quarter: 32 rows
    const int wcB = (wave & 1)*128;          // col half for stages A/B (N=256)
    const int lr = lane & 15, g0 = lane >> 4;

    // ---- precomputed staging bases (per lane, once) ----
    const int rA_  = wave*16 + (lane >> 2);
    const int gA_  = (lane & 3) ^ ((rA_ >> 1) & 3);
    const int eA_  = row0 + rA_;
    const ushort* baseSrc = nf16  + (size_t)(eA_/KN)*NDIM + gA_*8;
    const ushort* baseDst = nf16  + (size_t)sdst[rA_]*NDIM + gA_*8;
    const ushort* baseRbf = rbf16 + (size_t)eA_*EDIM + gA_*8;
    const uint ldsA_ = (uint)(wave*16)*32;
    const ushort* baseW1[4]; const ushort* baseW2[4];
    uint ldsBq[4];
#pragma unroll
    for (int q = 0; q < 4; ++q) {
        const int rowb = wave*64 + q*16 + (lane >> 2);
        const int gB = (lane & 3) ^ ((rowb >> 1) & 3);
        baseW1[q] = eW1t + (size_t)rowb*320 + gB*8;
        baseW2[q] = eW2t + (size_t)rowb*256 + gB*8;
        ldsBq[q] = (uint)(wave*64 + q*16)*32;
    }
    const ushort* baseC[2];
    uint ldsCq[2];
#pragma unroll
    for (int q = 0; q < 2; ++q) {
        const int rowb = wave*32 + q*16 + (lane >> 2);
        const int gB = (lane & 3) ^ ((rowb >> 1) & 3);
        baseC[q] = cW1t + (size_t)rowb*256 + gB*8;
        ldsCq[q] = (uint)(wave*32 + q*16)*32;
    }

    // ---------------- Stage A: h1 = silu(ef @ eW1 + eb1), K=320 ----------------
    auto STAGEA = [&](int k0) {
        const ushort* gp = (k0 < NDIM) ? baseSrc + k0
                         : (k0 < 2*NDIM) ? baseDst + (k0 - NDIM)
                         : baseRbf + (k0 - 2*NDIM);
        gl_lds(gp, As + ldsA_);
#pragma unroll
        for (int q = 0; q < 4; ++q)
            gl_lds(baseW1[q] + k0, Bs + ldsBq[q]);
    };
    f32x4 acc[2][8];
#pragma unroll
    for (int m = 0; m < 2; ++m)
#pragma unroll
        for (int n = 0; n < 8; ++n) acc[m][n] = (f32x4){0.f,0.f,0.f,0.f};
    STAGEA(0);
#pragma unroll
    for (int it = 0; it < 10; ++it) {
        asm volatile("s_waitcnt vmcnt(0)" ::: "memory");
        __builtin_amdgcn_s_barrier();
        bf16x8 af[2], bfr[8];
#pragma unroll
        for (int m = 0; m < 2; ++m) {
            const int rA = wr + m*16 + lr;
            af[m] = *reinterpret_cast<const bf16x8*>(&As[rA*32 + ((g0 ^ ((rA>>1)&3)))*8]);
        }
#pragma unroll
        for (int n = 0; n < 8; ++n) {
            const int rB = wcB + n*16 + lr;
            bfr[n] = *reinterpret_cast<const bf16x8*>(&Bs[rB*32 + ((g0 ^ ((rB>>1)&3)))*8]);
        }
        __builtin_amdgcn_s_setprio(1);
#pragma unroll
        for (int m = 0; m < 2; ++m)
#pragma unroll
            for (int n = 0; n < 8; ++n)
                acc[m][n] = __builtin_amdgcn_mfma_f32_16x16x32_bf16(af[m], bfr[n], acc[m][n], 0, 0, 0);
        __builtin_amdgcn_s_setprio(0);
        asm volatile("s_waitcnt lgkmcnt(0)" ::: "memory");
        __builtin_amdgcn_s_barrier();
        if (it + 1 < 10) STAGEA((it + 1)*32);
    }
    // prefetch stage B tile 0 (R1, free during stage A) -- hides under epilogue A
    {
#pragma unroll
        for (int q = 0; q < 4; ++q)
            gl_lds(baseW2[q], B2 + ldsBq[q]);
    }
    // epilogue A: h1 -> Hs (swizzled, overlays As/Bs)
#pragma unroll
    for (int n = 0; n < 8; ++n) {
        const int cc = wcB + n*16 + lr;
        const float b1 = eb1[cc];
#pragma unroll
        for (int m = 0; m < 2; ++m) {
#pragma unroll
            for (int j = 0; j < 4; ++j) {
                const int rr = wr + m*16 + g0*4 + j;
                const float x = siluf(acc[m][n][j] + b1);
                *(ushort*)(R0 + rr*512 + ((cc*2) ^ ((rr&7)<<4))) = f2b(x);
            }
        }
    }
    __syncthreads();

    // ---------------- Stage B: msg = silu(h1 @ eW2 + eb2), K=256 ----------------
#pragma unroll
    for (int m = 0; m < 2; ++m)
#pragma unroll
        for (int n = 0; n < 8; ++n) acc[m][n] = (f32x4){0.f,0.f,0.f,0.f};
#pragma unroll
    for (int it = 0; it < 8; ++it) {
        asm volatile("s_waitcnt vmcnt(0)" ::: "memory");
        __builtin_amdgcn_s_barrier();
        bf16x8 af[2], bfr[8];
#pragma unroll
        for (int m = 0; m < 2; ++m) {
            const int rA = wr + m*16 + lr;
            const int kc = it*4 + g0;
            af[m] = *reinterpret_cast<const bf16x8*>(R0 + rA*512 + ((kc*16) ^ ((rA&7)<<4)));
        }
#pragma unroll
        for (int n = 0; n < 8; ++n) {
            const int rB = wcB + n*16 + lr;
            bfr[n] = *reinterpret_cast<const bf16x8*>(&B2[rB*32 + ((g0 ^ ((rB>>1)&3)))*8]);
        }
        __builtin_amdgcn_s_setprio(1);
#pragma unroll
        for (int m = 0; m < 2; ++m)
#pragma unroll
            for (int n = 0; n < 8; ++n)
                acc[m][n] = __builtin_amdgcn_mfma_f32_16x16x32_bf16(af[m], bfr[n], acc[m][n], 0, 0, 0);
        __builtin_amdgcn_s_setprio(0);
        asm volatile("s_waitcnt lgkmcnt(0)" ::: "memory");
        __builtin_amdgcn_s_barrier();
        if (it + 1 < 8) {
            const int k0 = (it + 1)*32;
#pragma unroll
            for (int q = 0; q < 4; ++q)
                gl_lds(baseW2[q] + k0, B2 + ldsBq[q]);
        }
    }
    // prefetch stage C tile 0 (Cs overlays B2; stage B reads fully drained)
    {
#pragma unroll
        for (int q = 0; q < 2; ++q)
            gl_lds(baseC[q], Cs + ldsCq[q]);
    }
    // epilogue B: msg -> Hs in place (global store deferred to kernel end)
#pragma unroll
    for (int n = 0; n < 8; ++n) {
        const int cc = wcB + n*16 + lr;
        const float b2 = eb2[cc];
#pragma unroll
        for (int m = 0; m < 2; ++m) {
#pragma unroll
            for (int j = 0; j < 4; ++j) {
                const int rr = wr + m*16 + g0*4 + j;
                *(ushort*)(R0 + rr*512 + ((cc*2) ^ ((rr&7)<<4))) = f2b(siluf(acc[m][n][j] + b2));
            }
        }
    }
    __syncthreads();

    // ---------------- Stage C: wv = silu(msg @ cW1 + cb1) . cW2 + cb2, K=256 ----------------
    const int wcC = (wave & 1)*64;
    f32x4 acc3[2][4];
#pragma unroll
    for (int m = 0; m < 2; ++m)
#pragma unroll
        for (int n = 0; n < 4; ++n) acc3[m][n] = (f32x4){0.f,0.f,0.f,0.f};
#pragma unroll
    for (int it = 0; it < 8; ++it) {
        asm volatile("s_waitcnt vmcnt(0)" ::: "memory");
        __builtin_amdgcn_s_barrier();
        bf16x8 af[2], bfr[4];
#pragma unroll
        for (int m = 0; m < 2; ++m) {
            const int rA = wr + m*16 + lr;
            const int kc = it*4 + g0;
            af[m] = *reinterpret_cast<const bf16x8*>(R0 + rA*512 + ((kc*16) ^ ((rA&7)<<4)));
        }
#pragma unroll
        for (int n = 0; n < 4; ++n) {
            const int rB = wcC + n*16 + lr;
            bfr[n] = *reinterpret_cast<const bf16x8*>(&Cs[rB*32 + ((g0 ^ ((rB>>1)&3)))*8]);
        }
        __builtin_amdgcn_s_setprio(1);
#pragma unroll
        for (int m = 0; m < 2; ++m)
#pragma unroll
            for (int n = 0; n < 4; ++n)
                acc3[m][n] = __builtin_amdgcn_mfma_f32_16x16x32_bf16(af[m], bfr[n], acc3[m][n], 0, 0, 0);
        __builtin_amdgcn_s_setprio(0);
        asm volatile("s_waitcnt lgkmcnt(0)" ::: "memory");
        __builtin_amdgcn_s_barrier();
        if (it + 1 < 8) {
            const int k0 = (it + 1)*32;
#pragma unroll
            for (int q = 0; q < 2; ++q)
                gl_lds(baseC[q] + k0, Cs + ldsCq[q]);
        }
    }
    float part[2][4];
#pragma unroll
    for (int m = 0; m < 2; ++m)
#pragma unroll
        for (int j = 0; j < 4; ++j) part[m][j] = 0.0f;
#pragma unroll
    for (int n = 0; n < 4; ++n) {
        const int cc = wcC + n*16 + lr;
        const float bb = cb1[cc];
        const float cw = cW2v[cc];
#pragma unroll
        for (int m = 0; m < 2; ++m)
#pragma unroll
            for (int j = 0; j < 4; ++j)
                part[m][j] += siluf(acc3[m][n][j] + bb) * cw;
    }
#pragma unroll
    for (int off = 1; off < 16; off <<= 1)
#pragma unroll
        for (int m = 0; m < 2; ++m)
#pragma unroll
            for (int j = 0; j < 4; ++j)
                part[m][j] += __shfl_xor(part[m][j], off, 64);
    if (lr == 0) {
#pragma unroll
        for (int m = 0; m < 2; ++m)
#pragma unroll
            for (int j = 0; j < 4; ++j)
                wred[wave & 1][wr + m*16 + g0*4 + j] = part[m][j];
    }
    __syncthreads();
    if (t < EB) wvout[row0 + t] = wred[0][t] + wred[1][t] + cb2v[0];
    // coalesced msg16 store from Hs (unswizzle on the fly): 8 x uint4 per thread
#pragma unroll
    for (int k = 0; k < 8; ++k) {
        const int off = (t + k*256) * 16;     // byte offset in Hs (32KB)
        const int row = off >> 9;
        const int cg = ((off >> 4) & 31) ^ (row & 7);
        uint4 v = *reinterpret_cast<const uint4*>(R0 + off);
        *reinterpret_cast<uint4*>(msg16 + (size_t)(row0 + row)*256 + cg*8) = v;
    }
}

// Fused node chain: t1 = silu([nf16|aggr16] @ nW1 + nb1); nf += t1 @ nW2 + nb2.
__global__ __launch_bounds__(256) void nodefused(
        const ushort* __restrict__ nf16, const ushort* __restrict__ aggr16,
        const ushort* __restrict__ nW1t,   // [256][384]
        const ushort* __restrict__ nW2t,   // [128][256]
        const float* __restrict__ nb1, const float* __restrict__ nb2,
        float* __restrict__ nf, ushort* __restrict__ nf16out) {
    __shared__ alignas(16) ushort Ab[12*2048];     // 48KB: 12 chunks of [64][32]
    __shared__ alignas(16) char HsB[32768];        // t1 tile, swizzled
    __shared__ alignas(16) ushort Bs[2][256*32];   // 32KB weight dbuf
    const int t = threadIdx.x, wave = t >> 6, lane = t & 63;
    const int r0 = blockIdx.x*64;
    const int wr = (wave >> 1)*32;
    const int wcB = (wave & 1)*128;
    const int lr = lane & 15, g0 = lane >> 4;

#pragma unroll
    for (int c = 0; c < 3; ++c) {
        const int ks = wave*3 + c;
#pragma unroll
        for (int q = 0; q < 4; ++q) {
            const int r = q*16 + (lane >> 2);
            const int g = (lane & 3) ^ ((r >> 1) & 3);
            const int col = ks*32 + g*8;
            const ushort* gp = (col < NDIM)
                ? nf16 + (size_t)(r0 + r)*NDIM + col
                : aggr16 + (size_t)(r0 + r)*HDIM + (col - NDIM);
            gl_lds(gp, Ab + ks*2048 + q*16*32);
        }
    }
    const ushort* baseW1[4];
    uint ldsBq[4];
#pragma unroll
    for (int q = 0; q < 4; ++q) {
        const int rowb = wave*64 + q*16 + (lane >> 2);
        const int gB = (lane & 3) ^ ((rowb >> 1) & 3);
        baseW1[q] = nW1t + (size_t)rowb*384 + gB*8;
        ldsBq[q] = (uint)(wave*64 + q*16)*32;
    }
    const ushort* baseW2[2];
    uint ldsCq[2];
#pragma unroll
    for (int q = 0; q < 2; ++q) {
        const int rowb = wave*32 + q*16 + (lane >> 2);
        const int gB = (lane & 3) ^ ((rowb >> 1) & 3);
        baseW2[q] = nW2t + (size_t)rowb*256 + gB*8;
        ldsCq[q] = (uint)(wave*32 + q*16)*32;
    }
#pragma unroll
    for (int q = 0; q < 4; ++q)
        gl_lds(baseW1[q], &Bs[0][ldsBq[q]]);
    asm volatile("s_waitcnt vmcnt(0)" ::: "memory");
    __builtin_amdgcn_s_barrier();

    f32x4 acc[2][8];
#pragma unroll
    for (int m = 0; m < 2; ++m)
#pragma unroll
        for (int n = 0; n < 8; ++n) acc[m][n] = (f32x4){0.f,0.f,0.f,0.f};
    int cur = 0;
#pragma unroll
    for (int it = 0; it < 12; ++it) {
        if (it + 1 < 12) {
            const int k0 = (it + 1)*32;
#pragma unroll
            for (int q = 0; q < 4; ++q)
                gl_lds(baseW1[q] + k0, &Bs[cur^1][ldsBq[q]]);
            asm volatile("s_waitcnt vmcnt(4)" ::: "memory");
        } else {
            asm volatile("s_waitcnt vmcnt(0)" ::: "memory");
        }
        __builtin_amdgcn_s_barrier();
        bf16x8 af[2], bfr[8];
#pragma unroll
        for (int m = 0; m < 2; ++m) {
            const int rA = wr + m*16 + lr;
            af[m] = *reinterpret_cast<const bf16x8*>(&Ab[it*2048 + rA*32 + ((g0 ^ ((rA>>1)&3)))*8]);
        }
#pragma unroll
        for (int n = 0; n < 8; ++n) {
            const int rB = wcB + n*16 + lr;
            bfr[n] = *reinterpret_cast<const bf16x8*>(&Bs[cur][rB*32 + ((g0 ^ ((rB>>1)&3)))*8]);
        }
        __builtin_amdgcn_s_setprio(1);
#pragma unroll
        for (int m = 0; m < 2; ++m)
#pragma unroll
            for (int n = 0; n < 8; ++n)
                acc[m][n] = __builtin_amdgcn_mfma_f32_16x16x32_bf16(af[m], bfr[n], acc[m][n], 0, 0, 0);
        __builtin_amdgcn_s_setprio(0);
        asm volatile("s_waitcnt lgkmcnt(0)" ::: "memory");
        __builtin_amdgcn_s_barrier();
        cur ^= 1;
    }
#pragma unroll
    for (int q = 0; q < 2; ++q)
        gl_lds(baseW2[q], &Bs[0][ldsCq[q]]);
#pragma unroll
    for (int n = 0; n < 8; ++n) {
        const int cc = wcB + n*16 + lr;
        const float b1 = nb1[cc];
#pragma unroll
        for (int m = 0; m < 2; ++m) {
#pragma unroll
            for (int j = 0; j < 4; ++j) {
                const int rr = wr + m*16 + g0*4 + j;
                *(ushort*)(HsB + rr*512 + ((cc*2) ^ ((rr&7)<<4))) = f2b(siluf(acc[m][n][j] + b1));
            }
        }
    }
    __syncthreads();

    const int wcC = (wave & 1)*64;
    f32x4 acc3[2][4];
#pragma unroll
    for (int m = 0; m < 2; ++m)
#pragma unroll
        for (int n = 0; n < 4; ++n) acc3[m][n] = (f32x4){0.f,0.f,0.f,0.f};
    cur = 0;
#pragma unroll
    for (int it = 0; it < 8; ++it) {
        if (it + 1 < 8) {
            const int k0 = (it + 1)*32;
#pragma unroll
            for (int q = 0; q < 2; ++q)
                gl_lds(baseW2[q] + k0, &Bs[cur^1][ldsCq[q]]);
            asm volatile("s_waitcnt vmcnt(2)" ::: "memory");
        } else {
            asm volatile("s_waitcnt vmcnt(0)" ::: "memory");
        }
        __builtin_amdgcn_s_barrier();
        bf16x8 af[2], bfr[4];
#pragma unroll
        for (int m = 0; m < 2; ++m) {
            const int rA = wr + m*16 + lr;
            const int kc = it*4 + g0;
            af[m] = *reinterpret_cast<const bf16x8*>(HsB + rA*512 + ((kc*16) ^ ((rA&7)<<4)));
        }
#pragma unroll
        for (int n = 0; n < 4; ++n) {
            const int rB = wcC + n*16 + lr;
            bfr[n] = *reinterpret_cast<const bf16x8*>(&Bs[cur][rB*32 + ((g0 ^ ((rB>>1)&3)))*8]);
        }
        __builtin_amdgcn_s_setprio(1);
#pragma unroll
        for (int m = 0; m < 2; ++m)
#pragma unroll
            for (int n = 0; n < 4; ++n)
                acc3[m][n] = __builtin_amdgcn_mfma_f32_16x16x32_bf16(af[m], bfr[n], acc3[m][n], 0, 0, 0);
        __builtin_amdgcn_s_setprio(0);
        asm volatile("s_waitcnt lgkmcnt(0)" ::: "memory");
        __builtin_amdgcn_s_barrier();
        cur ^= 1;
    }
#pragma unroll
    for (int n = 0; n < 4; ++n) {
        const int cc = wcC + n*16 + lr;
        const float b2 = nb2[cc];
#pragma unroll
        for (int m = 0; m < 2; ++m) {
#pragma unroll
            for (int j = 0; j < 4; ++j) {
                const int rr = r0 + wr + m*16 + g0*4 + j;
                float x = acc3[m][n][j] + b2 + nf[(size_t)rr*NDIM + cc];
                nf[(size_t)rr*NDIM + cc] = x;
                nf16out[(size_t)rr*NDIM + cc] = f2b(x);
            }
        }
    }
}

// merged per-node kernel: aggr (segment-sum of msg) + coords update. One wave per node.
__global__ void node_kernel(const ushort* __restrict__ msg16, const float* __restrict__ cold,
                            const float* __restrict__ wv, const int* __restrict__ ccnt,
                            const int* __restrict__ cedg,
                            ushort* __restrict__ aggr16, float* __restrict__ cnew) {
    __shared__ int se[4][64];
    const int w = threadIdx.x >> 6, lane = threadIdx.x & 63;
    const int j = blockIdx.x*4 + w;
    const int cnt = min(ccnt[j], MAXDEG);
    se[w][lane] = (lane < cnt) ? cedg[(size_t)j*MAXDEG + lane] : 0;
    __syncthreads();
    const int c4 = lane*4;
    float s0 = 0, s1 = 0, s2 = 0, s3 = 0;
    const int lim = min(cnt, 64);
    for (int q = 0; q < lim; ++q) {
        const int e = se[w][q];
        ushort4 v = *reinterpret_cast<const ushort4*>(&msg16[(size_t)e*HDIM + c4]);
        s0 += b2f(v.x); s1 += b2f(v.y); s2 += b2f(v.z); s3 += b2f(v.w);
    }
    for (int q = 64; q < cnt; ++q) {
        const int e = cedg[(size_t)j*MAXDEG + q];
        ushort4 v = *reinterpret_cast<const ushort4*>(&msg16[(size_t)e*HDIM + c4]);
        s0 += b2f(v.x); s1 += b2f(v.y); s2 += b2f(v.z); s3 += b2f(v.w);
    }
    ushort4 o; o.x = f2b(s0); o.y = f2b(s1); o.z = f2b(s2); o.w = f2b(s3);
    *reinterpret_cast<ushort4*>(&aggr16[(size_t)j*HDIM + c4]) = o;
    const float jx = cold[j*3], jy = cold[j*3+1], jz = cold[j*3+2];
    float dx = 0, dy = 0, dz = 0;
    for (int q = lane; q < cnt; q += 64) {
        const int e = (q < 64) ? se[w][q] : cedg[(size_t)j*MAXDEG + q];
        const int si = e / KN;
        const float ax = cold[si*3]   - jx;
        const float ay = cold[si*3+1] - jy;
        const float az = cold[si*3+2] - jz;
        const float inv = wv[e] / (sqrtf(ax*ax + ay*ay + az*az) + 1e-8f);
        dx += inv*ax; dy += inv*ay; dz += inv*az;
    }
    for (int off = 32; off > 0; off >>= 1) {
        dx += __shfl_xor(dx, off, 64);
        dy += __shfl_xor(dy, off, 64);
        dz += __shfl_xor(dz, off, 64);
    }
    if (lane == 0) {
        cnew[j*3]   = jx + dx;
        cnew[j*3+1] = jy + dy;
        cnew[j*3+2] = jz + dz;
    }
}

__global__ void copyout_kernel(const float* __restrict__ nf, const float* __restrict__ coords,
                               float* __restrict__ out) {
    int idx = blockIdx.x*256 + threadIdx.x;
    if (idx < NA*NDIM) out[idx] = nf[idx];
    else if (idx < NA*NDIM + NA*3) out[idx] = coords[idx - NA*NDIM];
}

extern "C" void kernel_launch(void* const* d_in, const int* in_sizes, int n_in,
                              void* d_out, int out_size, void* d_ws, size_t ws_size,
                              hipStream_t stream) {
    const int*   atom_types = (const int*)  d_in[0];
    const float* frac       = (const float*)d_in[1];
    const float* lengths    = (const float*)d_in[2];
    const float* angles     = (const float*)d_in[3];
    const float* timesteps  = (const float*)d_in[4];
    const float* emb        = (const float*)d_in[5];
    const float* tW         = (const float*)d_in[6];
    const float* tb         = (const float*)d_in[7];
    const float* eW1        = (const float*)d_in[8];
    const float* eb1        = (const float*)d_in[9];
    const float* eW2        = (const float*)d_in[10];
    const float* eb2        = (const float*)d_in[11];
    const float* nW1        = (const float*)d_in[12];
    const float* nb1        = (const float*)d_in[13];
    const float* nW2        = (const float*)d_in[14];
    const float* nb2        = (const float*)d_in[15];
    const float* cW1        = (const float*)d_in[16];
    const float* cb1        = (const float*)d_in[17];
    const float* cW2        = (const float*)d_in[18];
    const float* cb2        = (const float*)d_in[19];

    char* p = (char*)d_ws;
    auto alloc = [&](size_t bytes) { char* q = p; p += (bytes + 255) & ~(size_t)255; return q; };
    float*  sv    = (float*) alloc(81*4);
    float*  c0    = (float*) alloc((size_t)NA*3*4);
    float*  c1    = (float*) alloc((size_t)NA*3*4);
    float*  cxg   = (float*) alloc((size_t)NA*4);
    float*  cyg   = (float*) alloc((size_t)NA*4);
    float*  czg   = (float*) alloc((size_t)NA*4);
    float*  nf    = (float*) alloc((size_t)NA*NDIM*4);
    int*    dstl  = (int*)   alloc((size_t)NE*4);
    ushort* rbf16 = (ushort*)alloc((size_t)NE*EDIM*2);
    int*    ccnt  = (int*)   alloc((size_t)NA*4);
    int*    cedg  = (int*)   alloc((size_t)NA*MAXDEG*4);
    ushort* aggr16= (ushort*)alloc((size_t)NA*HDIM*2);
    float*  wv    = (float*) alloc((size_t)NE*4);
    ushort* nf16  = (ushort*)alloc((size_t)NA*NDIM*2);
    ushort* msg16 = (ushort*)alloc((size_t)NE*HDIM*2);
    ushort* eW1t  = (ushort*)alloc((size_t)NLAYER*(2*NDIM+EDIM)*HDIM*2);
    ushort* eW2t  = (ushort*)alloc((size_t)NLAYER*HDIM*HDIM*2);
    ushort* cW1t  = (ushort*)alloc((size_t)NLAYER*(HDIM/2)*HDIM*2);
    ushort* nW1t  = (ushort*)alloc((size_t)NLAYER*(NDIM+HDIM)*HDIM*2);
    ushort* nW2t  = (ushort*)alloc((size_t)NLAYER*HDIM*NDIM*2);

    setup_kernel<<<8, 256, 0, stream>>>(frac, lengths, angles, c0, cxg, cyg, czg, sv, ccnt);
    knn_kernel<<<NA, 64, 0, stream>>>(cxg, cyg, czg, lengths, angles, sv,
                                      dstl, rbf16, ccnt, cedg);
    csort_kernel<<<NA/4, 256, 0, stream>>>(ccnt, cedg);
    nf_init_kernel<<<NA, 128, 0, stream>>>(atom_types, timesteps, emb, tW, tb, nf, nf16);
    wprep_all<<<304, 256, 0, stream>>>(eW1, eW2, cW1, nW1, nW2,
                                       eW1t, eW2t, cW1t, nW1t, nW2t);

    float* cin = c0; float* cout = c1;
    for (int l = 0; l < NLAYER; ++l) {
        const float* eb1l = eb1 + (size_t)l*HDIM;
        const float* eb2l = eb2 + (size_t)l*HDIM;
        const float* nb1l = nb1 + (size_t)l*HDIM;
        const float* nb2l = nb2 + (size_t)l*NDIM;
        const float* cb1l = cb1 + (size_t)l*(HDIM/2);
        const float* cW2l = cW2 + (size_t)l*(HDIM/2);
        const float* cb2l = cb2 + (size_t)l;

        // fused edge chain: h1 -> msg -> wv
        edge_fused<<<NE/EB, 256, 0, stream>>>(
            nf16, dstl, rbf16,
            eW1t + (size_t)l*(2*NDIM+EDIM)*HDIM, eW2t + (size_t)l*HDIM*HDIM,
            cW1t + (size_t)l*(HDIM/2)*HDIM,
            eb1l, eb2l, cb1l, cW2l, cb2l, msg16, wv);
        // aggr + coords (merged)
        node_kernel<<<NA/4, 256, 0, stream>>>(msg16, cin, wv, ccnt, cedg, aggr16, cout);
        // fused node chain: t1 -> nf update
        nodefused<<<NA/64, 256, 0, stream>>>(
            nf16, aggr16, nW1t + (size_t)l*(NDIM+HDIM)*HDIM, nW2t + (size_t)l*HDIM*NDIM,
            nb1l, nb2l, nf, nf16);
        float* tmp = cin; cin = cout; cout = tmp;
    }
    copyout_kernel<<<(NA*NDIM + NA*3)/256, 256, 0, stream>>>(nf, cin, (float*)d_out);
}

// Round 16
// 368.289 us; speedup vs baseline: 1.0278x; 1.0278x over previous
//
#include <hip/hip_runtime.h>
#include <math.h>

#define NA 2048          // atoms
#define KN 24            // neighbors per atom
#define NE (NA*KN)       // edges = 49152
#define NDIM 128         // node dim
#define EDIM 64          // rbf dim
#define HDIM 256         // hidden dim
#define NLAYER 4
#define MAXDEG 256       // cap on in-degree for CSR
#define EB 64            // edges per block in edge_fused

typedef __attribute__((ext_vector_type(8))) short bf16x8;
typedef __attribute__((ext_vector_type(4))) float f32x4;

// fast silu: x * rcp(1+exp(-x)). 1-ulp transcendental error, invisible under bf16 quant.
__device__ __forceinline__ float siluf(float x) {
    return __fdividef(x, 1.0f + __expf(-x));
}
__device__ __forceinline__ ushort f2b(float x) {  // RNE float->bf16
    unsigned u = __float_as_uint(x);
    return (ushort)((u + 0x7fffu + ((u >> 16) & 1u)) >> 16);
}
__device__ __forceinline__ float b2f(ushort h) { return __uint_as_float(((unsigned)h) << 16); }

// async global->LDS, 16B per lane. LDS dest = wave-uniform base + lane*16 (linear).
__device__ __forceinline__ void gl_lds(const void* g, void* lds) {
    __builtin_amdgcn_global_load_lds(
        (const __attribute__((address_space(1))) unsigned int*)g,
        (__attribute__((address_space(3))) unsigned int*)lds, 16, 0, 0);
}

struct Lat { float lx, xy, xz, ly, yz, lz; };

__device__ __forceinline__ Lat make_lattice(const float* lengths, const float* angles) {
    const float deg = 0.017453292519943295f;
    float a = lengths[0], b = lengths[1], c = lengths[2];
    float al = angles[0]*deg, be = angles[1]*deg, ga = angles[2]*deg;
    Lat L;
    L.lx = a;
    L.xy = b * cosf(ga);
    L.xz = c * cosf(be);
    L.ly = b * sinf(ga);
    L.yz = (b*c*cosf(al) - L.xy*L.xz) / L.ly;
    L.lz = sqrtf(c*c - L.xz*L.xz - L.yz*L.yz);
    return L;
}

// writes AoS cart + SoA cx/cy/cz; also zeroes ccnt (used by knn's fused scatter)
__global__ void setup_kernel(const float* __restrict__ frac, const float* __restrict__ lengths,
                             const float* __restrict__ angles, float* __restrict__ cart,
                             float* __restrict__ cxg, float* __restrict__ cyg,
                             float* __restrict__ czg, float* __restrict__ sv,
                             int* __restrict__ ccnt) {
    int i = blockIdx.x*blockDim.x + threadIdx.x;
    Lat L = make_lattice(lengths, angles);
    if (i < NA) {
        float f0 = frac[i*3], f1 = frac[i*3+1], f2 = frac[i*3+2];
        float x = f0*L.lx + f1*L.xy + f2*L.xz;
        float y = f1*L.ly + f2*L.yz;
        float z = f2*L.lz;
        cart[i*3+0] = x; cart[i*3+1] = y; cart[i*3+2] = z;
        cxg[i] = x; cyg[i] = y; czg[i] = z;
        ccnt[i] = 0;
    }
    if (i < 27) {
        float s0 = (float)(i/9 - 1), s1 = (float)((i/3)%3 - 1), s2 = (float)(i%3 - 1);
        sv[i*3+0] = s0*L.lx + s1*L.xy + s2*L.xz;
        sv[i*3+1] = s1*L.ly + s2*L.yz;
        sv[i*3+2] = s2*L.lz;
    }
}

// Per-atom top-24 + fused RBF + fused CSR scatter. One 64-lane wave per atom.
__global__ __launch_bounds__(64) void knn_kernel(
        const float* __restrict__ cxg, const float* __restrict__ cyg,
        const float* __restrict__ czg, const float* __restrict__ lengths,
        const float* __restrict__ angles, const float* __restrict__ sv,
        int* __restrict__ dstl, ushort* __restrict__ rbf16,
        int* __restrict__ ccnt, int* __restrict__ cedg) {
    __shared__ float sd2L[16][64];
    __shared__ int   sfL[16][64];
    const int lane = threadIdx.x;
    const int i = blockIdx.x;
    Lat L = make_lattice(lengths, angles);
    const float deg = 0.017453292519943295f;
    const bool ortho = fabsf(cosf(angles[0]*deg)) < 1e-6f &&
                       fabsf(cosf(angles[1]*deg)) < 1e-6f &&
                       fabsf(cosf(angles[2]*deg)) < 1e-6f;
    const float cx = cxg[i], cy = cyg[i], cz = czg[i];
    const float invlx = 1.0f/L.lx, invly = 1.0f/L.ly, invlz = 1.0f/L.lz;
    float R = 2.8f;
    int mycnt = 0, cnt = 0;
    bool flatm = false;
    for (int attempt = 0; attempt < 8; ++attempt) {
        const float R2 = R*R;
        mycnt = 0;
        flatm = !ortho || (attempt == 7);
        if (!flatm) {
#pragma unroll 2
            for (int j0 = 0; j0 < NA; j0 += 64) {
                const int j = j0 + lane;
                const float dx = cxg[j] - cx, dy = cyg[j] - cy, dz = czg[j] - cz;
                const float kx = rintf(dx*invlx), ky = rintf(dy*invly), kz = rintf(dz*invlz);
                const float ex = dx - (kx*L.lx + ky*L.xy + kz*L.xz);
                const float ey = dy - (ky*L.ly + kz*L.yz);
                const float ez = dz - kz*L.lz;
                const float d2 = fmaf(ex,ex,fmaf(ey,ey,ez*ez));
                if (d2 < R2 && d2 > 1e-4f) {
                    const int s = (1-(int)kx)*9 + (1-(int)ky)*3 + (1-(int)kz);
                    if (mycnt < 16) { sd2L[mycnt][lane] = d2; sfL[mycnt][lane] = (s<<11) + j; }
                    ++mycnt;
                }
            }
            if (__ballot(mycnt > 16)) {
                flatm = true;
            } else {
                int tot = mycnt;
                for (int off = 32; off > 0; off >>= 1) tot += __shfl_xor(tot, off, 64);
                cnt = tot;
            }
        }
        if (flatm) {
            cnt = 0;
            for (int s = 0; s < 27; ++s) {
                const float svx = sv[s*3], svy = sv[s*3+1], svz = sv[s*3+2];
                for (int j0 = 0; j0 < NA; j0 += 64) {
                    const int j = j0 + lane;
                    const float ex = cxg[j] + svx - cx;
                    const float ey = cyg[j] + svy - cy;
                    const float ez = czg[j] + svz - cz;
                    const float d2 = fmaf(ex,ex,fmaf(ey,ey,ez*ez));
                    const bool hit = (d2 < R2) && (d2 > 1e-4f);
                    const unsigned long long m = __ballot(hit);
                    const int rank = __popcll(m & ((1ull<<lane)-1ull));
                    const int slot = cnt + rank;
                    if (hit && slot < 1024) { sd2L[slot>>6][slot&63] = d2; sfL[slot>>6][slot&63] = (s<<11)+j; }
                    cnt += __popcll(m);
                }
            }
            cnt = min(cnt, 1024);
        }
        if (cnt >= KN) break;
        R = fminf(R*1.6f, flatm ? 8.0f : 5.9f);
    }
    int vq;
    if (flatm) vq = (lane < cnt) ? min(16, ((cnt - 1 - lane) >> 6) + 1) : 0;
    else       vq = mycnt;
    unsigned long long key[16];
#pragma unroll
    for (int q = 0; q < 16; ++q) {
        const float d2v = sd2L[q][lane];
        const int fl = sfL[q][lane];
        const unsigned long long kk = ((unsigned long long)__float_as_uint(d2v) << 20)
                                    | ((unsigned long long)(unsigned)fl << 4) | (unsigned)q;
        key[q] = (q < vq) ? kk : ~0ull;
    }
    float der[KN];
    for (int k = 0; k < KN; ++k) {
        unsigned long long lm = key[0];
#pragma unroll
        for (int q = 1; q < 16; ++q) lm = key[q] < lm ? key[q] : lm;
        for (int off = 32; off > 0; off >>= 1) {
            unsigned long long o = __shfl_xor(lm, off, 64);
            lm = o < lm ? o : lm;
        }
        der[k] = sqrtf(__uint_as_float((unsigned)(lm >> 20)));
        if (lane == 0) {
            const int jn = (int)((lm >> 4) & 2047u);
            dstl[i*KN + k] = jn;
            const int slot = atomicAdd(&ccnt[jn], 1);
            if (slot < MAXDEG) cedg[(size_t)jn*MAXDEG + slot] = i*KN + k;
        }
#pragma unroll
        for (int q = 0; q < 16; ++q) if (key[q] == lm) key[q] = ~0ull;
    }
    const float center = (8.0f/63.0f) * (float)lane;
    for (int k = 0; k < KN; ++k) {
        const float d = der[k];
        const float diff = d - center;
        const float g = __expf(diff*diff * -32.0f);
        const float cv = 0.5f * (__cosf(d * (float)(M_PI/8.0)) + 1.0f);
        rbf16[(size_t)(i*KN + k)*EDIM + lane] = f2b(g * cv);
    }
}

// one wave per node: 64-lane bitonic sort (ascending), serial fallback for cnt>64
__global__ void csort_kernel(const int* __restrict__ ccnt, int* __restrict__ cedg) {
    const int j = blockIdx.x*4 + (threadIdx.x >> 6);
    const int lane = threadIdx.x & 63;
    const int cnt = min(ccnt[j], MAXDEG);
    if (cnt <= 64) {
        int v = (lane < cnt) ? cedg[(size_t)j*MAXDEG + lane] : 0x7FFFFFFF;
#pragma unroll
        for (int k = 2; k <= 64; k <<= 1) {
#pragma unroll
            for (int s = k >> 1; s > 0; s >>= 1) {
                int o = __shfl_xor(v, s, 64);
                const bool up = ((lane & k) == 0);
                const bool lowhalf = ((lane & s) == 0);
                v = ((lowhalf == up) ? min(v, o) : max(v, o));
            }
        }
        if (lane < cnt) cedg[(size_t)j*MAXDEG + lane] = v;
    } else if (lane == 0) {
        int* L = cedg + (size_t)j*MAXDEG;
        for (int a = 1; a < cnt; ++a) {
            int v = L[a]; int b = a - 1;
            while (b >= 0 && L[b] > v) { L[b+1] = L[b]; --b; }
            L[b+1] = v;
        }
    }
}

__global__ void nf_init_kernel(const int* __restrict__ atom_types, const float* __restrict__ ts,
                               const float* __restrict__ emb, const float* __restrict__ tW,
                               const float* __restrict__ tb, float* __restrict__ nf,
                               ushort* __restrict__ nf16) {
    int i = blockIdx.x, c = threadIdx.x;  // 128 threads
    float acc = emb[atom_types[i]*NDIM + c] + tb[c];
    for (int kk = 0; kk < 128; ++kk) acc += ts[i*128 + kk] * tW[kk*NDIM + c];
    nf[i*NDIM + c] = acc;
    nf16[i*NDIM + c] = f2b(acc);
}

// LDS-tiled transpose+convert: Wt[l][n][k] = bf16(W[l][k][n]). 64x64 tiles.
__global__ void wprep_all(const float* __restrict__ eW1, const float* __restrict__ eW2,
                          const float* __restrict__ cW1, const float* __restrict__ nW1,
                          const float* __restrict__ nW2,
                          ushort* __restrict__ eW1t, ushort* __restrict__ eW2t,
                          ushort* __restrict__ cW1t, ushort* __restrict__ nW1t,
                          ushort* __restrict__ nW2t) {
    __shared__ float tile[64][65];
    const int b = blockIdx.x;
    const float* W; ushort* Wt; int Kk, Nn, rel;
    if (b < 80)       { W = eW1; Wt = eW1t; Kk = 320; Nn = 256; rel = b; }
    else if (b < 144) { W = eW2; Wt = eW2t; Kk = 256; Nn = 256; rel = b - 80; }
    else if (b < 176) { W = cW1; Wt = cW1t; Kk = 256; Nn = 128; rel = b - 144; }
    else if (b < 272) { W = nW1; Wt = nW1t; Kk = 384; Nn = 256; rel = b - 176; }
    else              { W = nW2; Wt = nW2t; Kk = 256; Nn = 128; rel = b - 272; }
    const int kt = Kk >> 6, nt = Nn >> 6, per = kt*nt;
    const int l = rel / per, r2 = rel - l*per;
    const int k0 = (r2 / nt) * 64, n0 = (r2 - (r2/nt)*nt) * 64;
    const float* Wl = W + (size_t)l*Kk*Nn;
    ushort* Wtl = Wt + (size_t)l*Kk*Nn;
    const int tr = threadIdx.x >> 6, tc = threadIdx.x & 63;
#pragma unroll
    for (int q = 0; q < 16; ++q) {
        const int k = q*4 + tr;
        tile[k][tc] = Wl[(size_t)(k0 + k)*Nn + n0 + tc];
    }
    __syncthreads();
#pragma unroll
    for (int q = 0; q < 16; ++q) {
        const int n = q*4 + tr;
        Wtl[(size_t)(n0 + n)*Kk + k0 + tc] = f2b(tile[tc][n]);
    }
}

// Fused edge chain: h1 -> msg -> wv. 64 edges/block, 256 threads (4 waves, 2x2).
// LDS 74752 B (2 blocks/CU). R14-proven config: dbuf weight staging, fast-math silu,
// no sched_barrier pins, stage-boundary prefetch, setprio around MFMA clusters.
// Hs (h1/msg tile, 64x256 bf16) swizzle: byte = row*512 + ((col*2) ^ ((row&7)<<4)).
__global__ __launch_bounds__(256) void edge_fused(
        const ushort* __restrict__ nf16, const int* __restrict__ dstl,
        const ushort* __restrict__ rbf16,
        const ushort* __restrict__ eW1t,   // [256][320]
        const ushort* __restrict__ eW2t,   // [256][256]
        const ushort* __restrict__ cW1t,   // [128][256]
        const float* __restrict__ eb1, const float* __restrict__ eb2,
        const float* __restrict__ cb1, const float* __restrict__ cW2v,
        const float* __restrict__ cb2v,
        ushort* __restrict__ msg16, float* __restrict__ wvout) {
    __shared__ alignas(16) char R0[40960];   // {As 8K | Bs 32K} -> overlay Hs 32K
    __shared__ alignas(16) char R1[32768];   // {B2 32K} -> overlay {Cs 16K}
    __shared__ int sdst[64];
    __shared__ float wred[2][64];
    ushort* As = (ushort*)R0;                // 2 x [64][32]
    ushort* Bs = (ushort*)(R0 + 8192);       // 2 x [256][32]
    ushort* B2 = (ushort*)R1;                // 2 x [256][32]
    ushort* Cs = (ushort*)R1;                // 2 x [128][32]

    const int t = threadIdx.x, wave = t >> 6, lane = t & 63;
    const int row0 = blockIdx.x*EB;
    if (t < EB) sdst[t] = dstl[row0 + t];
    __syncthreads();
    const int wr = (wave >> 1)*32;           // row quarter: 32 rows
    const int wcB = (wave & 1)*128;          // col half for stages A/B (N=256)
    const int lr = lane & 15, g0 = lane >> 4;

    // ---- precomputed staging bases (per lane, once) ----
    const int rA_  = wave*16 + (lane >> 2);
    const int gA_  = (lane & 3) ^ ((rA_ >> 1) & 3);
    const int eA_  = row0 + rA_;
    const ushort* baseSrc = nf16  + (size_t)(eA_/KN)*NDIM + gA_*8;
    const ushort* baseDst = nf16  + (size_t)sdst[rA_]*NDIM + gA_*8;
    const ushort* baseRbf = rbf16 + (size_t)eA_*EDIM + gA_*8;
    const uint ldsA_ = (uint)(wave*16)*32;
    const ushort* baseW1[4]; const ushort* baseW2[4];
    uint ldsBq[4];
#pragma unroll
    for (int q = 0; q < 4; ++q) {
        const int rowb = wave*64 + q*16 + (lane >> 2);
        const int gB = (lane & 3) ^ ((rowb >> 1) & 3);
        baseW1[q] = eW1t + (size_t)rowb*320 + gB*8;
        baseW2[q] = eW2t + (size_t)rowb*256 + gB*8;
        ldsBq[q] = (uint)(wave*64 + q*16)*32;
    }
    const ushort* baseC[2];
    uint ldsCq[2];
#pragma unroll
    for (int q = 0; q < 2; ++q) {
        const int rowb = wave*32 + q*16 + (lane >> 2);
        const int gB = (lane & 3) ^ ((rowb >> 1) & 3);
        baseC[q] = cW1t + (size_t)rowb*256 + gB*8;
        ldsCq[q] = (uint)(wave*32 + q*16)*32;
    }

    // ---------------- Stage A: h1 = silu(ef @ eW1 + eb1), K=320 ----------------
    auto STAGEA = [&](int buf, int k0) {
        const ushort* gp = (k0 < NDIM) ? baseSrc + k0
                         : (k0 < 2*NDIM) ? baseDst + (k0 - NDIM)
                         : baseRbf + (k0 - 2*NDIM);
        gl_lds(gp, As + (size_t)buf*2048 + ldsA_);
#pragma unroll
        for (int q = 0; q < 4; ++q)
            gl_lds(baseW1[q] + k0, Bs + (size_t)buf*8192 + ldsBq[q]);
    };
    f32x4 acc[2][8];
#pragma unroll
    for (int m = 0; m < 2; ++m)
#pragma unroll
        for (int n = 0; n < 8; ++n) acc[m][n] = (f32x4){0.f,0.f,0.f,0.f};
    STAGEA(0, 0);
    int cur = 0;
#pragma unroll
    for (int it = 0; it < 10; ++it) {
        if (it + 1 < 10) {
            STAGEA(cur ^ 1, (it + 1)*32);
            asm volatile("s_waitcnt vmcnt(5)" ::: "memory");
        } else {
            asm volatile("s_waitcnt vmcnt(0)" ::: "memory");
        }
        __builtin_amdgcn_s_barrier();
        bf16x8 af[2], bfr[8];
#pragma unroll
        for (int m = 0; m < 2; ++m) {
            const int rA = wr + m*16 + lr;
            af[m] = *reinterpret_cast<const bf16x8*>(&As[cur*2048 + rA*32 + ((g0 ^ ((rA>>1)&3)))*8]);
        }
#pragma unroll
        for (int n = 0; n < 8; ++n) {
            const int rB = wcB + n*16 + lr;
            bfr[n] = *reinterpret_cast<const bf16x8*>(&Bs[(size_t)cur*8192 + rB*32 + ((g0 ^ ((rB>>1)&3)))*8]);
        }
        __builtin_amdgcn_s_setprio(1);
#pragma unroll
        for (int m = 0; m < 2; ++m)
#pragma unroll
            for (int n = 0; n < 8; ++n)
                acc[m][n] = __builtin_amdgcn_mfma_f32_16x16x32_bf16(af[m], bfr[n], acc[m][n], 0, 0, 0);
        __builtin_amdgcn_s_setprio(0);
        asm volatile("s_waitcnt lgkmcnt(0)" ::: "memory");
        __builtin_amdgcn_s_barrier();
        cur ^= 1;
    }
    // prefetch stage B buf0 -- hides under epilogue A
    {
#pragma unroll
        for (int q = 0; q < 4; ++q)
            gl_lds(baseW2[q], B2 + ldsBq[q]);
    }
    // epilogue A: h1 -> Hs (swizzled, overlays As/Bs)
#pragma unroll
    for (int n = 0; n < 8; ++n) {
        const int cc = wcB + n*16 + lr;
        const float b1 = eb1[cc];
#pragma unroll
        for (int m = 0; m < 2; ++m) {
#pragma unroll
            for (int j = 0; j < 4; ++j) {
                const int rr = wr + m*16 + g0*4 + j;
                const float x = siluf(acc[m][n][j] + b1);
                *(ushort*)(R0 + rr*512 + ((cc*2) ^ ((rr&7)<<4))) = f2b(x);
            }
        }
    }
    __syncthreads();

    // ---------------- Stage B: msg = silu(h1 @ eW2 + eb2), K=256 ----------------
#pragma unroll
    for (int m = 0; m < 2; ++m)
#pragma unroll
        for (int n = 0; n < 8; ++n) acc[m][n] = (f32x4){0.f,0.f,0.f,0.f};
    cur = 0;
#pragma unroll
    for (int it = 0; it < 8; ++it) {
        if (it + 1 < 8) {
            const int k0 = (it + 1)*32;
#pragma unroll
            for (int q = 0; q < 4; ++q)
                gl_lds(baseW2[q] + k0, B2 + (size_t)(cur^1)*8192 + ldsBq[q]);
            asm volatile("s_waitcnt vmcnt(4)" ::: "memory");
        } else {
            asm volatile("s_waitcnt vmcnt(0)" ::: "memory");
        }
        __builtin_amdgcn_s_barrier();
        bf16x8 af[2], bfr[8];
#pragma unroll
        for (int m = 0; m < 2; ++m) {
            const int rA = wr + m*16 + lr;
            const int kc = it*4 + g0;
            af[m] = *reinterpret_cast<const bf16x8*>(R0 + rA*512 + ((kc*16) ^ ((rA&7)<<4)));
        }
#pragma unroll
        for (int n = 0; n < 8; ++n) {
            const int rB = wcB + n*16 + lr;
            bfr[n] = *reinterpret_cast<const bf16x8*>(&B2[(size_t)cur*8192 + rB*32 + ((g0 ^ ((rB>>1)&3)))*8]);
        }
        __builtin_amdgcn_s_setprio(1);
#pragma unroll
        for (int m = 0; m < 2; ++m)
#pragma unroll
            for (int n = 0; n < 8; ++n)
                acc[m][n] = __builtin_amdgcn_mfma_f32_16x16x32_bf16(af[m], bfr[n], acc[m][n], 0, 0, 0);
        __builtin_amdgcn_s_setprio(0);
        asm volatile("s_waitcnt lgkmcnt(0)" ::: "memory");
        __builtin_amdgcn_s_barrier();
        cur ^= 1;
    }
    // prefetch stage C buf0 -- hides under epilogue B
    {
#pragma unroll
        for (int q = 0; q < 2; ++q)
            gl_lds(baseC[q], Cs + ldsCq[q]);
    }
    // epilogue B: msg -> Hs in place (global store deferred to kernel end)
#pragma unroll
    for (int n = 0; n < 8; ++n) {
        const int cc = wcB + n*16 + lr;
        const float b2 = eb2[cc];
#pragma unroll
        for (int m = 0; m < 2; ++m) {
#pragma unroll
            for (int j = 0; j < 4; ++j) {
                const int rr = wr + m*16 + g0*4 + j;
                *(ushort*)(R0 + rr*512 + ((cc*2) ^ ((rr&7)<<4))) = f2b(siluf(acc[m][n][j] + b2));
            }
        }
    }
    __syncthreads();

    // ---------------- Stage C: wv = silu(msg @ cW1 + cb1) . cW2 + cb2, K=256 ----------------
    const int wcC = (wave & 1)*64;
    f32x4 acc3[2][4];
#pragma unroll
    for (int m = 0; m < 2; ++m)
#pragma unroll
        for (int n = 0; n < 4; ++n) acc3[m][n] = (f32x4){0.f,0.f,0.f,0.f};
    cur = 0;
#pragma unroll
    for (int it = 0; it < 8; ++it) {
        if (it + 1 < 8) {
            const int k0 = (it + 1)*32;
#pragma unroll
            for (int q = 0; q < 2; ++q)
                gl_lds(baseC[q] + k0, Cs + (size_t)(cur^1)*4096 + ldsCq[q]);
            asm volatile("s_waitcnt vmcnt(2)" ::: "memory");
        } else {
            asm volatile("s_waitcnt vmcnt(0)" ::: "memory");
        }
        __builtin_amdgcn_s_barrier();
        bf16x8 af[2], bfr[4];
#pragma unroll
        for (int m = 0; m < 2; ++m) {
            const int rA = wr + m*16 + lr;
            const int kc = it*4 + g0;
            af[m] = *reinterpret_cast<const bf16x8*>(R0 + rA*512 + ((kc*16) ^ ((rA&7)<<4)));
        }
#pragma unroll
        for (int n = 0; n < 4; ++n) {
            const int rB = wcC + n*16 + lr;
            bfr[n] = *reinterpret_cast<const bf16x8*>(&Cs[(size_t)cur*4096 + rB*32 + ((g0 ^ ((rB>>1)&3)))*8]);
        }
        __builtin_amdgcn_s_setprio(1);
#pragma unroll
        for (int m = 0; m < 2; ++m)
#pragma unroll
            for (int n = 0; n < 4; ++n)
                acc3[m][n] = __builtin_amdgcn_mfma_f32_16x16x32_bf16(af[m], bfr[n], acc3[m][n], 0, 0, 0);
        __builtin_amdgcn_s_setprio(0);
        asm volatile("s_waitcnt lgkmcnt(0)" ::: "memory");
        __builtin_amdgcn_s_barrier();
        cur ^= 1;
    }
    float part[2][4];
#pragma unroll
    for (int m = 0; m < 2; ++m)
#pragma unroll
        for (int j = 0; j < 4; ++j) part[m][j] = 0.0f;
#pragma unroll
    for (int n = 0; n < 4; ++n) {
        const int cc = wcC + n*16 + lr;
        const float bb = cb1[cc];
        const float cw = cW2v[cc];
#pragma unroll
        for (int m = 0; m < 2; ++m)
#pragma unroll
            for (int j = 0; j < 4; ++j)
                part[m][j] += siluf(acc3[m][n][j] + bb) * cw;
    }
#pragma unroll
    for (int off = 1; off < 16; off <<= 1)
#pragma unroll
        for (int m = 0; m < 2; ++m)
#pragma unroll
            for (int j = 0; j < 4; ++j)
                part[m][j] += __shfl_xor(part[m][j], off, 64);
    if (lr == 0) {
#pragma unroll
        for (int m = 0; m < 2; ++m)
#pragma unroll
            for (int j = 0; j < 4; ++j)
                wred[wave & 1][wr + m*16 + g0*4 + j] = part[m][j];
    }
    __syncthreads();
    if (t < EB) wvout[row0 + t] = wred[0][t] + wred[1][t] + cb2v[0];
    // coalesced msg16 store from Hs (unswizzle on the fly): 8 x uint4 per thread
#pragma unroll
    for (int k = 0; k < 8; ++k) {
        const int off = (t + k*256) * 16;     // byte offset in Hs (32KB)
        const int row = off >> 9;
        const int cg = ((off >> 4) & 31) ^ (row & 7);
        uint4 v = *reinterpret_cast<const uint4*>(R0 + off);
        *reinterpret_cast<uint4*>(msg16 + (size_t)(row0 + row)*256 + cg*8) = v;
    }
}

// Fused node chain: t1 = silu([nf16|aggr16] @ nW1 + nb1); nf += t1 @ nW2 + nb2.
__global__ __launch_bounds__(256) void nodefused(
        const ushort* __restrict__ nf16, const ushort* __restrict__ aggr16,
        const ushort* __restrict__ nW1t,   // [256][384]
        const ushort* __restrict__ nW2t,   // [128][256]
        const float* __restrict__ nb1, const float* __restrict__ nb2,
        float* __restrict__ nf, ushort* __restrict__ nf16out) {
    __shared__ alignas(16) ushort Ab[12*2048];     // 48KB: 12 chunks of [64][32]
    __shared__ alignas(16) char HsB[32768];        // t1 tile, swizzled
    __shared__ alignas(16) ushort Bs[2][256*32];   // 32KB weight dbuf
    const int t = threadIdx.x, wave = t >> 6, lane = t & 63;
    const int r0 = blockIdx.x*64;
    const int wr = (wave >> 1)*32;
    const int wcB = (wave & 1)*128;
    const int lr = lane & 15, g0 = lane >> 4;

#pragma unroll
    for (int c = 0; c < 3; ++c) {
        const int ks = wave*3 + c;
#pragma unroll
        for (int q = 0; q < 4; ++q) {
            const int r = q*16 + (lane >> 2);
            const int g = (lane & 3) ^ ((r >> 1) & 3);
            const int col = ks*32 + g*8;
            const ushort* gp = (col < NDIM)
                ? nf16 + (size_t)(r0 + r)*NDIM + col
                : aggr16 + (size_t)(r0 + r)*HDIM + (col - NDIM);
            gl_lds(gp, Ab + ks*2048 + q*16*32);
        }
    }
    const ushort* baseW1[4];
    uint ldsBq[4];
#pragma unroll
    for (int q = 0; q < 4; ++q) {
        const int rowb = wave*64 + q*16 + (lane >> 2);
        const int gB = (lane & 3) ^ ((rowb >> 1) & 3);
        baseW1[q] = nW1t + (size_t)rowb*384 + gB*8;
        ldsBq[q] = (uint)(wave*64 + q*16)*32;
    }
    const ushort* baseW2[2];
    uint ldsCq[2];
#pragma unroll
    for (int q = 0; q < 2; ++q) {
        const int rowb = wave*32 + q*16 + (lane >> 2);
        const int gB = (lane & 3) ^ ((rowb >> 1) & 3);
        baseW2[q] = nW2t + (size_t)rowb*256 + gB*8;
        ldsCq[q] = (uint)(wave*32 + q*16)*32;
    }
#pragma unroll
    for (int q = 0; q < 4; ++q)
        gl_lds(baseW1[q], &Bs[0][ldsBq[q]]);
    asm volatile("s_waitcnt vmcnt(0)" ::: "memory");
    __builtin_amdgcn_s_barrier();

    f32x4 acc[2][8];
#pragma unroll
    for (int m = 0; m < 2; ++m)
#pragma unroll
        for (int n = 0; n < 8; ++n) acc[m][n] = (f32x4){0.f,0.f,0.f,0.f};
    int cur = 0;
#pragma unroll
    for (int it = 0; it < 12; ++it) {
        if (it + 1 < 12) {
            const int k0 = (it + 1)*32;
#pragma unroll
            for (int q = 0; q < 4; ++q)
                gl_lds(baseW1[q] + k0, &Bs[cur^1][ldsBq[q]]);
            asm volatile("s_waitcnt vmcnt(4)" ::: "memory");
        } else {
            asm volatile("s_waitcnt vmcnt(0)" ::: "memory");
        }
        __builtin_amdgcn_s_barrier();
        bf16x8 af[2], bfr[8];
#pragma unroll
        for (int m = 0; m < 2; ++m) {
            const int rA = wr + m*16 + lr;
            af[m] = *reinterpret_cast<const bf16x8*>(&Ab[it*2048 + rA*32 + ((g0 ^ ((rA>>1)&3)))*8]);
        }
#pragma unroll
        for (int n = 0; n < 8; ++n) {
            const int rB = wcB + n*16 + lr;
            bfr[n] = *reinterpret_cast<const bf16x8*>(&Bs[cur][rB*32 + ((g0 ^ ((rB>>1)&3)))*8]);
        }
        __builtin_amdgcn_s_setprio(1);
#pragma unroll
        for (int m = 0; m < 2; ++m)
#pragma unroll
            for (int n = 0; n < 8; ++n)
                acc[m][n] = __builtin_amdgcn_mfma_f32_16x16x32_bf16(af[m], bfr[n], acc[m][n], 0, 0, 0);
        __builtin_amdgcn_s_setprio(0);
        asm volatile("s_waitcnt lgkmcnt(0)" ::: "memory");
        __builtin_amdgcn_s_barrier();
        cur ^= 1;
    }
#pragma unroll
    for (int q = 0; q < 2; ++q)
        gl_lds(baseW2[q], &Bs[0][ldsCq[q]]);
#pragma unroll
    for (int n = 0; n < 8; ++n) {
        const int cc = wcB + n*16 + lr;
        const float b1 = nb1[cc];
#pragma unroll
        for (int m = 0; m < 2; ++m) {
#pragma unroll
            for (int j = 0; j < 4; ++j) {
                const int rr = wr + m*16 + g0*4 + j;
                *(ushort*)(HsB + rr*512 + ((cc*2) ^ ((rr&7)<<4))) = f2b(siluf(acc[m][n][j] + b1));
            }
        }
    }
    __syncthreads();

    const int wcC = (wave & 1)*64;
    f32x4 acc3[2][4];
#pragma unroll
    for (int m = 0; m < 2; ++m)
#pragma unroll
        for (int n = 0; n < 4; ++n) acc3[m][n] = (f32x4){0.f,0.f,0.f,0.f};
    cur = 0;
#pragma unroll
    for (int it = 0; it < 8; ++it) {
        if (it + 1 < 8) {
            const int k0 = (it + 1)*32;
#pragma unroll
            for (int q = 0; q < 2; ++q)
                gl_lds(baseW2[q] + k0, &Bs[cur^1][ldsCq[q]]);
            asm volatile("s_waitcnt vmcnt(2)" ::: "memory");
        } else {
            asm volatile("s_waitcnt vmcnt(0)" ::: "memory");
        }
        __builtin_amdgcn_s_barrier();
        bf16x8 af[2], bfr[4];
#pragma unroll
        for (int m = 0; m < 2; ++m) {
            const int rA = wr + m*16 + lr;
            const int kc = it*4 + g0;
            af[m] = *reinterpret_cast<const bf16x8*>(HsB + rA*512 + ((kc*16) ^ ((rA&7)<<4)));
        }
#pragma unroll
        for (int n = 0; n < 4; ++n) {
            const int rB = wcC + n*16 + lr;
            bfr[n] = *reinterpret_cast<const bf16x8*>(&Bs[cur][rB*32 + ((g0 ^ ((rB>>1)&3)))*8]);
        }
        __builtin_amdgcn_s_setprio(1);
#pragma unroll
        for (int m = 0; m < 2; ++m)
#pragma unroll
            for (int n = 0; n < 4; ++n)
                acc3[m][n] = __builtin_amdgcn_mfma_f32_16x16x32_bf16(af[m], bfr[n], acc3[m][n], 0, 0, 0);
        __builtin_amdgcn_s_setprio(0);
        asm volatile("s_waitcnt lgkmcnt(0)" ::: "memory");
        __builtin_amdgcn_s_barrier();
        cur ^= 1;
    }
#pragma unroll
    for (int n = 0; n < 4; ++n) {
        const int cc = wcC + n*16 + lr;
        const float b2 = nb2[cc];
#pragma unroll
        for (int m = 0; m < 2; ++m) {
#pragma unroll
            for (int j = 0; j < 4; ++j) {
                const int rr = r0 + wr + m*16 + g0*4 + j;
                float x = acc3[m][n][j] + b2 + nf[(size_t)rr*NDIM + cc];
                nf[(size_t)rr*NDIM + cc] = x;
                nf16out[(size_t)rr*NDIM + cc] = f2b(x);
            }
        }
    }
}

// merged per-node kernel: aggr (segment-sum of msg) + coords update. One wave per node.
__global__ void node_kernel(const ushort* __restrict__ msg16, const float* __restrict__ cold,
                            const float* __restrict__ wv, const int* __restrict__ ccnt,
                            const int* __restrict__ cedg,
                            ushort* __restrict__ aggr16, float* __restrict__ cnew) {
    __shared__ int se[4][64];
    const int w = threadIdx.x >> 6, lane = threadIdx.x & 63;
    const int j = blockIdx.x*4 + w;
    const int cnt = min(ccnt[j], MAXDEG);
    se[w][lane] = (lane < cnt) ? cedg[(size_t)j*MAXDEG + lane] : 0;
    __syncthreads();
    const int c4 = lane*4;
    float s0 = 0, s1 = 0, s2 = 0, s3 = 0;
    const int lim = min(cnt, 64);
    for (int q = 0; q < lim; ++q) {
        const int e = se[w][q];
        ushort4 v = *reinterpret_cast<const ushort4*>(&msg16[(size_t)e*HDIM + c4]);
        s0 += b2f(v.x); s1 += b2f(v.y); s2 += b2f(v.z); s3 += b2f(v.w);
    }
    for (int q = 64; q < cnt; ++q) {
        const int e = cedg[(size_t)j*MAXDEG + q];
        ushort4 v = *reinterpret_cast<const ushort4*>(&msg16[(size_t)e*HDIM + c4]);
        s0 += b2f(v.x); s1 += b2f(v.y); s2 += b2f(v.z); s3 += b2f(v.w);
    }
    ushort4 o; o.x = f2b(s0); o.y = f2b(s1); o.z = f2b(s2); o.w = f2b(s3);
    *reinterpret_cast<ushort4*>(&aggr16[(size_t)j*HDIM + c4]) = o;
    const float jx = cold[j*3], jy = cold[j*3+1], jz = cold[j*3+2];
    float dx = 0, dy = 0, dz = 0;
    for (int q = lane; q < cnt; q += 64) {
        const int e = (q < 64) ? se[w][q] : cedg[(size_t)j*MAXDEG + q];
        const int si = e / KN;
        const float ax = cold[si*3]   - jx;
        const float ay = cold[si*3+1] - jy;
        const float az = cold[si*3+2] - jz;
        const float inv = wv[e] / (sqrtf(ax*ax + ay*ay + az*az) + 1e-8f);
        dx += inv*ax; dy += inv*ay; dz += inv*az;
    }
    for (int off = 32; off > 0; off >>= 1) {
        dx += __shfl_xor(dx, off, 64);
        dy += __shfl_xor(dy, off, 64);
        dz += __shfl_xor(dz, off, 64);
    }
    if (lane == 0) {
        cnew[j*3]   = jx + dx;
        cnew[j*3+1] = jy + dy;
        cnew[j*3+2] = jz + dz;
    }
}

__global__ void copyout_kernel(const float* __restrict__ nf, const float* __restrict__ coords,
                               float* __restrict__ out) {
    int idx = blockIdx.x*256 + threadIdx.x;
    if (idx < NA*NDIM) out[idx] = nf[idx];
    else if (idx < NA*NDIM + NA*3) out[idx] = coords[idx - NA*NDIM];
}

extern "C" void kernel_launch(void* const* d_in, const int* in_sizes, int n_in,
                              void* d_out, int out_size, void* d_ws, size_t ws_size,
                              hipStream_t stream) {
    const int*   atom_types = (const int*)  d_in[0];
    const float* frac       = (const float*)d_in[1];
    const float* lengths    = (const float*)d_in[2];
    const float* angles     = (const float*)d_in[3];
    const float* timesteps  = (const float*)d_in[4];
    const float* emb        = (const float*)d_in[5];
    const float* tW         = (const float*)d_in[6];
    const float* tb         = (const float*)d_in[7];
    const float* eW1        = (const float*)d_in[8];
    const float* eb1        = (const float*)d_in[9];
    const float* eW2        = (const float*)d_in[10];
    const float* eb2        = (const float*)d_in[11];
    const float* nW1        = (const float*)d_in[12];
    const float* nb1        = (const float*)d_in[13];
    const float* nW2        = (const float*)d_in[14];
    const float* nb2        = (const float*)d_in[15];
    const float* cW1        = (const float*)d_in[16];
    const float* cb1        = (const float*)d_in[17];
    const float* cW2        = (const float*)d_in[18];
    const float* cb2        = (const float*)d_in[19];

    char* p = (char*)d_ws;
    auto alloc = [&](size_t bytes) { char* q = p; p += (bytes + 255) & ~(size_t)255; return q; };
    float*  sv    = (float*) alloc(81*4);
    float*  c0    = (float*) alloc((size_t)NA*3*4);
    float*  c1    = (float*) alloc((size_t)NA*3*4);
    float*  cxg   = (float*) alloc((size_t)NA*4);
    float*  cyg   = (float*) alloc((size_t)NA*4);
    float*  czg   = (float*) alloc((size_t)NA*4);
    float*  nf    = (float*) alloc((size_t)NA*NDIM*4);
    int*    dstl  = (int*)   alloc((size_t)NE*4);
    ushort* rbf16 = (ushort*)alloc((size_t)NE*EDIM*2);
    int*    ccnt  = (int*)   alloc((size_t)NA*4);
    int*    cedg  = (int*)   alloc((size_t)NA*MAXDEG*4);
    ushort* aggr16= (ushort*)alloc((size_t)NA*HDIM*2);
    float*  wv    = (float*) alloc((size_t)NE*4);
    ushort* nf16  = (ushort*)alloc((size_t)NA*NDIM*2);
    ushort* msg16 = (ushort*)alloc((size_t)NE*HDIM*2);
    ushort* eW1t  = (ushort*)alloc((size_t)NLAYER*(2*NDIM+EDIM)*HDIM*2);
    ushort* eW2t  = (ushort*)alloc((size_t)NLAYER*HDIM*HDIM*2);
    ushort* cW1t  = (ushort*)alloc((size_t)NLAYER*(HDIM/2)*HDIM*2);
    ushort* nW1t  = (ushort*)alloc((size_t)NLAYER*(NDIM+HDIM)*HDIM*2);
    ushort* nW2t  = (ushort*)alloc((size_t)NLAYER*HDIM*NDIM*2);

    setup_kernel<<<8, 256, 0, stream>>>(frac, lengths, angles, c0, cxg, cyg, czg, sv, ccnt);
    knn_kernel<<<NA, 64, 0, stream>>>(cxg, cyg, czg, lengths, angles, sv,
                                      dstl, rbf16, ccnt, cedg);
    csort_kernel<<<NA/4, 256, 0, stream>>>(ccnt, cedg);
    nf_init_kernel<<<NA, 128, 0, stream>>>(atom_types, timesteps, emb, tW, tb, nf, nf16);
    wprep_all<<<304, 256, 0, stream>>>(eW1, eW2, cW1, nW1, nW2,
                                       eW1t, eW2t, cW1t, nW1t, nW2t);

    float* cin = c0; float* cout = c1;
    for (int l = 0; l < NLAYER; ++l) {
        const float* eb1l = eb1 + (size_t)l*HDIM;
        const float* eb2l = eb2 + (size_t)l*HDIM;
        const float* nb1l = nb1 + (size_t)l*HDIM;
        const float* nb2l = nb2 + (size_t)l*NDIM;
        const float* cb1l = cb1 + (size_t)l*(HDIM/2);
        const float* cW2l = cW2 + (size_t)l*(HDIM/2);
        const float* cb2l = cb2 + (size_t)l;

        // fused edge chain: h1 -> msg -> wv
        edge_fused<<<NE/EB, 256, 0, stream>>>(
            nf16, dstl, rbf16,
            eW1t + (size_t)l*(2*NDIM+EDIM)*HDIM, eW2t + (size_t)l*HDIM*HDIM,
            cW1t + (size_t)l*(HDIM/2)*HDIM,
            eb1l, eb2l, cb1l, cW2l, cb2l, msg16, wv);
        // aggr + coords (merged)
        node_kernel<<<NA/4, 256, 0, stream>>>(msg16, cin, wv, ccnt, cedg, aggr16, cout);
        // fused node chain: t1 -> nf update
        nodefused<<<NA/64, 256, 0, stream>>>(
            nf16, aggr16, nW1t + (size_t)l*(NDIM+HDIM)*HDIM, nW2t + (size_t)l*HDIM*NDIM,
            nb1l, nb2l, nf, nf16);
        float* tmp = cin; cin = cout; cout = tmp;
    }
    copyout_kernel<<<(NA*NDIM + NA*3)/256, 256, 0, stream>>>(nf, cin, (float*)d_out);
}

// Round 17
// 362.610 us; speedup vs baseline: 1.0439x; 1.0157x over previous
//
#include <hip/hip_runtime.h>
#include <hip/hip_bf16.h>
#include <math.h>

#define NA 2048          // atoms
#define KN 24            // neighbors per atom
#define NE (NA*KN)       // edges = 49152
#define NDIM 128         // node dim
#define EDIM 64          // rbf dim
#define HDIM 256         // hidden dim
#define NLAYER 4
#define MAXDEG 256       // cap on in-degree for CSR
#define EB 64            // edges per block in edge_fused

typedef __attribute__((ext_vector_type(8))) short bf16x8;
typedef __attribute__((ext_vector_type(4))) float f32x4;

// fast silu: x * rcp(1+exp(-x)). 1-ulp transcendental error, invisible under bf16 quant.
__device__ __forceinline__ float siluf(float x) {
    return __fdividef(x, 1.0f + __expf(-x));
}
// RNE float->bf16 via builtin (bit-identical to manual round-to-nearest-even;
// lets the compiler select packed cvt ops in unrolled epilogues)
__device__ __forceinline__ ushort f2b(float x) {
    __hip_bfloat16 h = __float2bfloat16(x);
    return *reinterpret_cast<ushort*>(&h);
}
__device__ __forceinline__ float b2f(ushort h) { return __uint_as_float(((unsigned)h) << 16); }

// async global->LDS, 16B per lane. LDS dest = wave-uniform base + lane*16 (linear).
__device__ __forceinline__ void gl_lds(const void* g, void* lds) {
    __builtin_amdgcn_global_load_lds(
        (const __attribute__((address_space(1))) unsigned int*)g,
        (__attribute__((address_space(3))) unsigned int*)lds, 16, 0, 0);
}

struct Lat { float lx, xy, xz, ly, yz, lz; };

__device__ __forceinline__ Lat make_lattice(const float* lengths, const float* angles) {
    const float deg = 0.017453292519943295f;
    float a = lengths[0], b = lengths[1], c = lengths[2];
    float al = angles[0]*deg, be = angles[1]*deg, ga = angles[2]*deg;
    Lat L;
    L.lx = a;
    L.xy = b * cosf(ga);
    L.xz = c * cosf(be);
    L.ly = b * sinf(ga);
    L.yz = (b*c*cosf(al) - L.xy*L.xz) / L.ly;
    L.lz = sqrtf(c*c - L.xz*L.xz - L.yz*L.yz);
    return L;
}

// writes AoS cart + SoA cx/cy/cz; also zeroes ccnt (used by knn's fused scatter)
__global__ void setup_kernel(const float* __restrict__ frac, const float* __restrict__ lengths,
                             const float* __restrict__ angles, float* __restrict__ cart,
                             float* __restrict__ cxg, float* __restrict__ cyg,
                             float* __restrict__ czg, float* __restrict__ sv,
                             int* __restrict__ ccnt) {
    int i = blockIdx.x*blockDim.x + threadIdx.x;
    Lat L = make_lattice(lengths, angles);
    if (i < NA) {
        float f0 = frac[i*3], f1 = frac[i*3+1], f2 = frac[i*3+2];
        float x = f0*L.lx + f1*L.xy + f2*L.xz;
        float y = f1*L.ly + f2*L.yz;
        float z = f2*L.lz;
        cart[i*3+0] = x; cart[i*3+1] = y; cart[i*3+2] = z;
        cxg[i] = x; cyg[i] = y; czg[i] = z;
        ccnt[i] = 0;
    }
    if (i < 27) {
        float s0 = (float)(i/9 - 1), s1 = (float)((i/3)%3 - 1), s2 = (float)(i%3 - 1);
        sv[i*3+0] = s0*L.lx + s1*L.xy + s2*L.xz;
        sv[i*3+1] = s1*L.ly + s2*L.yz;
        sv[i*3+2] = s2*L.lz;
    }
}

// Per-atom top-24 + fused RBF + fused CSR scatter. One 64-lane wave per atom.
__global__ __launch_bounds__(64) void knn_kernel(
        const float* __restrict__ cxg, const float* __restrict__ cyg,
        const float* __restrict__ czg, const float* __restrict__ lengths,
        const float* __restrict__ angles, const float* __restrict__ sv,
        int* __restrict__ dstl, ushort* __restrict__ rbf16,
        int* __restrict__ ccnt, int* __restrict__ cedg) {
    __shared__ float sd2L[16][64];
    __shared__ int   sfL[16][64];
    const int lane = threadIdx.x;
    const int i = blockIdx.x;
    Lat L = make_lattice(lengths, angles);
    const float deg = 0.017453292519943295f;
    const bool ortho = fabsf(cosf(angles[0]*deg)) < 1e-6f &&
                       fabsf(cosf(angles[1]*deg)) < 1e-6f &&
                       fabsf(cosf(angles[2]*deg)) < 1e-6f;
    const float cx = cxg[i], cy = cyg[i], cz = czg[i];
    const float invlx = 1.0f/L.lx, invly = 1.0f/L.ly, invlz = 1.0f/L.lz;
    float R = 2.8f;
    int mycnt = 0, cnt = 0;
    bool flatm = false;
    for (int attempt = 0; attempt < 8; ++attempt) {
        const float R2 = R*R;
        mycnt = 0;
        flatm = !ortho || (attempt == 7);
        if (!flatm) {
#pragma unroll 2
            for (int j0 = 0; j0 < NA; j0 += 64) {
                const int j = j0 + lane;
                const float dx = cxg[j] - cx, dy = cyg[j] - cy, dz = czg[j] - cz;
                const float kx = rintf(dx*invlx), ky = rintf(dy*invly), kz = rintf(dz*invlz);
                const float ex = dx - (kx*L.lx + ky*L.xy + kz*L.xz);
                const float ey = dy - (ky*L.ly + kz*L.yz);
                const float ez = dz - kz*L.lz;
                const float d2 = fmaf(ex,ex,fmaf(ey,ey,ez*ez));
                if (d2 < R2 && d2 > 1e-4f) {
                    const int s = (1-(int)kx)*9 + (1-(int)ky)*3 + (1-(int)kz);
                    if (mycnt < 16) { sd2L[mycnt][lane] = d2; sfL[mycnt][lane] = (s<<11) + j; }
                    ++mycnt;
                }
            }
            if (__ballot(mycnt > 16)) {
                flatm = true;
            } else {
                int tot = mycnt;
                for (int off = 32; off > 0; off >>= 1) tot += __shfl_xor(tot, off, 64);
                cnt = tot;
            }
        }
        if (flatm) {
            cnt = 0;
            for (int s = 0; s < 27; ++s) {
                const float svx = sv[s*3], svy = sv[s*3+1], svz = sv[s*3+2];
                for (int j0 = 0; j0 < NA; j0 += 64) {
                    const int j = j0 + lane;
                    const float ex = cxg[j] + svx - cx;
                    const float ey = cyg[j] + svy - cy;
                    const float ez = czg[j] + svz - cz;
                    const float d2 = fmaf(ex,ex,fmaf(ey,ey,ez*ez));
                    const bool hit = (d2 < R2) && (d2 > 1e-4f);
                    const unsigned long long m = __ballot(hit);
                    const int rank = __popcll(m & ((1ull<<lane)-1ull));
                    const int slot = cnt + rank;
                    if (hit && slot < 1024) { sd2L[slot>>6][slot&63] = d2; sfL[slot>>6][slot&63] = (s<<11)+j; }
                    cnt += __popcll(m);
                }
            }
            cnt = min(cnt, 1024);
        }
        if (cnt >= KN) break;
        R = fminf(R*1.6f, flatm ? 8.0f : 5.9f);
    }
    int vq;
    if (flatm) vq = (lane < cnt) ? min(16, ((cnt - 1 - lane) >> 6) + 1) : 0;
    else       vq = mycnt;
    unsigned long long key[16];
#pragma unroll
    for (int q = 0; q < 16; ++q) {
        const float d2v = sd2L[q][lane];
        const int fl = sfL[q][lane];
        const unsigned long long kk = ((unsigned long long)__float_as_uint(d2v) << 20)
                                    | ((unsigned long long)(unsigned)fl << 4) | (unsigned)q;
        key[q] = (q < vq) ? kk : ~0ull;
    }
    float der[KN];
    for (int k = 0; k < KN; ++k) {
        unsigned long long lm = key[0];
#pragma unroll
        for (int q = 1; q < 16; ++q) lm = key[q] < lm ? key[q] : lm;
        for (int off = 32; off > 0; off >>= 1) {
            unsigned long long o = __shfl_xor(lm, off, 64);
            lm = o < lm ? o : lm;
        }
        der[k] = sqrtf(__uint_as_float((unsigned)(lm >> 20)));
        if (lane == 0) {
            const int jn = (int)((lm >> 4) & 2047u);
            dstl[i*KN + k] = jn;
            const int slot = atomicAdd(&ccnt[jn], 1);
            if (slot < MAXDEG) cedg[(size_t)jn*MAXDEG + slot] = i*KN + k;
        }
#pragma unroll
        for (int q = 0; q < 16; ++q) if (key[q] == lm) key[q] = ~0ull;
    }
    const float center = (8.0f/63.0f) * (float)lane;
    for (int k = 0; k < KN; ++k) {
        const float d = der[k];
        const float diff = d - center;
        const float g = __expf(diff*diff * -32.0f);
        const float cv = 0.5f * (__cosf(d * (float)(M_PI/8.0)) + 1.0f);
        rbf16[(size_t)(i*KN + k)*EDIM + lane] = f2b(g * cv);
    }
}

// one wave per node: 64-lane bitonic sort (ascending), serial fallback for cnt>64
__global__ void csort_kernel(const int* __restrict__ ccnt, int* __restrict__ cedg) {
    const int j = blockIdx.x*4 + (threadIdx.x >> 6);
    const int lane = threadIdx.x & 63;
    const int cnt = min(ccnt[j], MAXDEG);
    if (cnt <= 64) {
        int v = (lane < cnt) ? cedg[(size_t)j*MAXDEG + lane] : 0x7FFFFFFF;
#pragma unroll
        for (int k = 2; k <= 64; k <<= 1) {
#pragma unroll
            for (int s = k >> 1; s > 0; s >>= 1) {
                int o = __shfl_xor(v, s, 64);
                const bool up = ((lane & k) == 0);
                const bool lowhalf = ((lane & s) == 0);
                v = ((lowhalf == up) ? min(v, o) : max(v, o));
            }
        }
        if (lane < cnt) cedg[(size_t)j*MAXDEG + lane] = v;
    } else if (lane == 0) {
        int* L = cedg + (size_t)j*MAXDEG;
        for (int a = 1; a < cnt; ++a) {
            int v = L[a]; int b = a - 1;
            while (b >= 0 && L[b] > v) { L[b+1] = L[b]; --b; }
            L[b+1] = v;
        }
    }
}

__global__ void nf_init_kernel(const int* __restrict__ atom_types, const float* __restrict__ ts,
                               const float* __restrict__ emb, const float* __restrict__ tW,
                               const float* __restrict__ tb, float* __restrict__ nf,
                               ushort* __restrict__ nf16) {
    int i = blockIdx.x, c = threadIdx.x;  // 128 threads
    float acc = emb[atom_types[i]*NDIM + c] + tb[c];
    for (int kk = 0; kk < 128; ++kk) acc += ts[i*128 + kk] * tW[kk*NDIM + c];
    nf[i*NDIM + c] = acc;
    nf16[i*NDIM + c] = f2b(acc);
}

// LDS-tiled transpose+convert: Wt[l][n][k] = bf16(W[l][k][n]). 64x64 tiles.
__global__ void wprep_all(const float* __restrict__ eW1, const float* __restrict__ eW2,
                          const float* __restrict__ cW1, const float* __restrict__ nW1,
                          const float* __restrict__ nW2,
                          ushort* __restrict__ eW1t, ushort* __restrict__ eW2t,
                          ushort* __restrict__ cW1t, ushort* __restrict__ nW1t,
                          ushort* __restrict__ nW2t) {
    __shared__ float tile[64][65];
    const int b = blockIdx.x;
    const float* W; ushort* Wt; int Kk, Nn, rel;
    if (b < 80)       { W = eW1; Wt = eW1t; Kk = 320; Nn = 256; rel = b; }
    else if (b < 144) { W = eW2; Wt = eW2t; Kk = 256; Nn = 256; rel = b - 80; }
    else if (b < 176) { W = cW1; Wt = cW1t; Kk = 256; Nn = 128; rel = b - 144; }
    else if (b < 272) { W = nW1; Wt = nW1t; Kk = 384; Nn = 256; rel = b - 176; }
    else              { W = nW2; Wt = nW2t; Kk = 256; Nn = 128; rel = b - 272; }
    const int kt = Kk >> 6, nt = Nn >> 6, per = kt*nt;
    const int l = rel / per, r2 = rel - l*per;
    const int k0 = (r2 / nt) * 64, n0 = (r2 - (r2/nt)*nt) * 64;
    const float* Wl = W + (size_t)l*Kk*Nn;
    ushort* Wtl = Wt + (size_t)l*Kk*Nn;
    const int tr = threadIdx.x >> 6, tc = threadIdx.x & 63;
#pragma unroll
    for (int q = 0; q < 16; ++q) {
        const int k = q*4 + tr;
        tile[k][tc] = Wl[(size_t)(k0 + k)*Nn + n0 + tc];
    }
    __syncthreads();
#pragma unroll
    for (int q = 0; q < 16; ++q) {
        const int n = q*4 + tr;
        Wtl[(size_t)(n0 + n)*Kk + k0 + tc] = f2b(tile[tc][n]);
    }
}

// Fused edge chain: h1 -> msg -> wv. 64 edges/block, 256 threads (4 waves, 2x2).
// LDS 74752 B (2 blocks/CU). R17: R14-proven config + builtin bf16 cvt in epilogues
// + redundant explicit lgkmcnt(0) drains removed (compiler's per-use lgkm waits
// already guarantee all ds_reads consumed before the barrier).
// Hs (h1/msg tile, 64x256 bf16) swizzle: byte = row*512 + ((col*2) ^ ((row&7)<<4)).
__global__ __launch_bounds__(256) void edge_fused(
        const ushort* __restrict__ nf16, const int* __restrict__ dstl,
        const ushort* __restrict__ rbf16,
        const ushort* __restrict__ eW1t,   // [256][320]
        const ushort* __restrict__ eW2t,   // [256][256]
        const ushort* __restrict__ cW1t,   // [128][256]
        const float* __restrict__ eb1, const float* __restrict__ eb2,
        const float* __restrict__ cb1, const float* __restrict__ cW2v,
        const float* __restrict__ cb2v,
        ushort* __restrict__ msg16, float* __restrict__ wvout) {
    __shared__ alignas(16) char R0[40960];   // {As 8K | Bs 32K} -> overlay Hs 32K
    __shared__ alignas(16) char R1[32768];   // {B2 32K} -> overlay {Cs 16K}
    __shared__ int sdst[64];
    __shared__ float wred[2][64];
    ushort* As = (ushort*)R0;                // 2 x [64][32]
    ushort* Bs = (ushort*)(R0 + 8192);       // 2 x [256][32]
    ushort* B2 = (ushort*)R1;                // 2 x [256][32]
    ushort* Cs = (ushort*)R1;                // 2 x [128][32]

    const int t = threadIdx.x, wave = t >> 6, lane = t & 63;
    const int row0 = blockIdx.x*EB;
    if (t < EB) sdst[t] = dstl[row0 + t];
    __syncthreads();
    const int wr = (wave >> 1)*32;           // row quarter: 32 rows
    const int wcB = (wave & 1)*128;          // col half for stages A/B (N=256)
    const int lr = lane & 15, g0 = lane >> 4;

    // ---- precomputed staging bases (per lane, once) ----
    const int rA_  = wave*16 + (lane >> 2);
    const int gA_  = (lane & 3) ^ ((rA_ >> 1) & 3);
    const int eA_  = row0 + rA_;
    const ushort* baseSrc = nf16  + (size_t)(eA_/KN)*NDIM + gA_*8;
    const ushort* baseDst = nf16  + (size_t)sdst[rA_]*NDIM + gA_*8;
    const ushort* baseRbf = rbf16 + (size_t)eA_*EDIM + gA_*8;
    const uint ldsA_ = (uint)(wave*16)*32;
    const ushort* baseW1[4]; const ushort* baseW2[4];
    uint ldsBq[4];
#pragma unroll
    for (int q = 0; q < 4; ++q) {
        const int rowb = wave*64 + q*16 + (lane >> 2);
        const int gB = (lane & 3) ^ ((rowb >> 1) & 3);
        baseW1[q] = eW1t + (size_t)rowb*320 + gB*8;
        baseW2[q] = eW2t + (size_t)rowb*256 + gB*8;
        ldsBq[q] = (uint)(wave*64 + q*16)*32;
    }
    const ushort* baseC[2];
    uint ldsCq[2];
#pragma unroll
    for (int q = 0; q < 2; ++q) {
        const int rowb = wave*32 + q*16 + (lane >> 2);
        const int gB = (lane & 3) ^ ((rowb >> 1) & 3);
        baseC[q] = cW1t + (size_t)rowb*256 + gB*8;
        ldsCq[q] = (uint)(wave*32 + q*16)*32;
    }

    // ---------------- Stage A: h1 = silu(ef @ eW1 + eb1), K=320 ----------------
    auto STAGEA = [&](int buf, int k0) {
        const ushort* gp = (k0 < NDIM) ? baseSrc + k0
                         : (k0 < 2*NDIM) ? baseDst + (k0 - NDIM)
                         : baseRbf + (k0 - 2*NDIM);
        gl_lds(gp, As + (size_t)buf*2048 + ldsA_);
#pragma unroll
        for (int q = 0; q < 4; ++q)
            gl_lds(baseW1[q] + k0, Bs + (size_t)buf*8192 + ldsBq[q]);
    };
    f32x4 acc[2][8];
#pragma unroll
    for (int m = 0; m < 2; ++m)
#pragma unroll
        for (int n = 0; n < 8; ++n) acc[m][n] = (f32x4){0.f,0.f,0.f,0.f};
    STAGEA(0, 0);
    int cur = 0;
#pragma unroll
    for (int it = 0; it < 10; ++it) {
        if (it + 1 < 10) {
            STAGEA(cur ^ 1, (it + 1)*32);
            asm volatile("s_waitcnt vmcnt(5)" ::: "memory");
        } else {
            asm volatile("s_waitcnt vmcnt(0)" ::: "memory");
        }
        __builtin_amdgcn_s_barrier();
        bf16x8 af[2], bfr[8];
#pragma unroll
        for (int m = 0; m < 2; ++m) {
            const int rA = wr + m*16 + lr;
            af[m] = *reinterpret_cast<const bf16x8*>(&As[cur*2048 + rA*32 + ((g0 ^ ((rA>>1)&3)))*8]);
        }
#pragma unroll
        for (int n = 0; n < 8; ++n) {
            const int rB = wcB + n*16 + lr;
            bfr[n] = *reinterpret_cast<const bf16x8*>(&Bs[(size_t)cur*8192 + rB*32 + ((g0 ^ ((rB>>1)&3)))*8]);
        }
        __builtin_amdgcn_s_setprio(1);
#pragma unroll
        for (int m = 0; m < 2; ++m)
#pragma unroll
            for (int n = 0; n < 8; ++n)
                acc[m][n] = __builtin_amdgcn_mfma_f32_16x16x32_bf16(af[m], bfr[n], acc[m][n], 0, 0, 0);
        __builtin_amdgcn_s_setprio(0);
        __builtin_amdgcn_s_barrier();
        cur ^= 1;
    }
    // prefetch stage B buf0 -- hides under epilogue A
    {
#pragma unroll
        for (int q = 0; q < 4; ++q)
            gl_lds(baseW2[q], B2 + ldsBq[q]);
    }
    // epilogue A: h1 -> Hs (swizzled, overlays As/Bs)
#pragma unroll
    for (int n = 0; n < 8; ++n) {
        const int cc = wcB + n*16 + lr;
        const float b1 = eb1[cc];
#pragma unroll
        for (int m = 0; m < 2; ++m) {
#pragma unroll
            for (int j = 0; j < 4; ++j) {
                const int rr = wr + m*16 + g0*4 + j;
                const float x = siluf(acc[m][n][j] + b1);
                *(ushort*)(R0 + rr*512 + ((cc*2) ^ ((rr&7)<<4))) = f2b(x);
            }
        }
    }
    __syncthreads();

    // ---------------- Stage B: msg = silu(h1 @ eW2 + eb2), K=256 ----------------
#pragma unroll
    for (int m = 0; m < 2; ++m)
#pragma unroll
        for (int n = 0; n < 8; ++n) acc[m][n] = (f32x4){0.f,0.f,0.f,0.f};
    cur = 0;
#pragma unroll
    for (int it = 0; it < 8; ++it) {
        if (it + 1 < 8) {
            const int k0 = (it + 1)*32;
#pragma unroll
            for (int q = 0; q < 4; ++q)
                gl_lds(baseW2[q] + k0, B2 + (size_t)(cur^1)*8192 + ldsBq[q]);
            asm volatile("s_waitcnt vmcnt(4)" ::: "memory");
        } else {
            asm volatile("s_waitcnt vmcnt(0)" ::: "memory");
        }
        __builtin_amdgcn_s_barrier();
        bf16x8 af[2], bfr[8];
#pragma unroll
        for (int m = 0; m < 2; ++m) {
            const int rA = wr + m*16 + lr;
            const int kc = it*4 + g0;
            af[m] = *reinterpret_cast<const bf16x8*>(R0 + rA*512 + ((kc*16) ^ ((rA&7)<<4)));
        }
#pragma unroll
        for (int n = 0; n < 8; ++n) {
            const int rB = wcB + n*16 + lr;
            bfr[n] = *reinterpret_cast<const bf16x8*>(&B2[(size_t)cur*8192 + rB*32 + ((g0 ^ ((rB>>1)&3)))*8]);
        }
        __builtin_amdgcn_s_setprio(1);
#pragma unroll
        for (int m = 0; m < 2; ++m)
#pragma unroll
            for (int n = 0; n < 8; ++n)
                acc[m][n] = __builtin_amdgcn_mfma_f32_16x16x32_bf16(af[m], bfr[n], acc[m][n], 0, 0, 0);
        __builtin_amdgcn_s_setprio(0);
        __builtin_amdgcn_s_barrier();
        cur ^= 1;
    }
    // prefetch stage C buf0 -- hides under epilogue B
    {
#pragma unroll
        for (int q = 0; q < 2; ++q)
            gl_lds(baseC[q], Cs + ldsCq[q]);
    }
    // epilogue B: msg -> Hs in place (global store deferred to kernel end)
#pragma unroll
    for (int n = 0; n < 8; ++n) {
        const int cc = wcB + n*16 + lr;
        const float b2 = eb2[cc];
#pragma unroll
        for (int m = 0; m < 2; ++m) {
#pragma unroll
            for (int j = 0; j < 4; ++j) {
                const int rr = wr + m*16 + g0*4 + j;
                *(ushort*)(R0 + rr*512 + ((cc*2) ^ ((rr&7)<<4))) = f2b(siluf(acc[m][n][j] + b2));
            }
        }
    }
    __syncthreads();

    // ---------------- Stage C: wv = silu(msg @ cW1 + cb1) . cW2 + cb2, K=256 ----------------
    const int wcC = (wave & 1)*64;
    f32x4 acc3[2][4];
#pragma unroll
    for (int m = 0; m < 2; ++m)
#pragma unroll
        for (int n = 0; n < 4; ++n) acc3[m][n] = (f32x4){0.f,0.f,0.f,0.f};
    cur = 0;
#pragma unroll
    for (int it = 0; it < 8; ++it) {
        if (it + 1 < 8) {
            const int k0 = (it + 1)*32;
#pragma unroll
            for (int q = 0; q < 2; ++q)
                gl_lds(baseC[q] + k0, Cs + (size_t)(cur^1)*4096 + ldsCq[q]);
            asm volatile("s_waitcnt vmcnt(2)" ::: "memory");
        } else {
            asm volatile("s_waitcnt vmcnt(0)" ::: "memory");
        }
        __builtin_amdgcn_s_barrier();
        bf16x8 af[2], bfr[4];
#pragma unroll
        for (int m = 0; m < 2; ++m) {
            const int rA = wr + m*16 + lr;
            const int kc = it*4 + g0;
            af[m] = *reinterpret_cast<const bf16x8*>(R0 + rA*512 + ((kc*16) ^ ((rA&7)<<4)));
        }
#pragma unroll
        for (int n = 0; n < 4; ++n) {
            const int rB = wcC + n*16 + lr;
            bfr[n] = *reinterpret_cast<const bf16x8*>(&Cs[(size_t)cur*4096 + rB*32 + ((g0 ^ ((rB>>1)&3)))*8]);
        }
        __builtin_amdgcn_s_setprio(1);
#pragma unroll
        for (int m = 0; m < 2; ++m)
#pragma unroll
            for (int n = 0; n < 4; ++n)
                acc3[m][n] = __builtin_amdgcn_mfma_f32_16x16x32_bf16(af[m], bfr[n], acc3[m][n], 0, 0, 0);
        __builtin_amdgcn_s_setprio(0);
        __builtin_amdgcn_s_barrier();
        cur ^= 1;
    }
    float part[2][4];
#pragma unroll
    for (int m = 0; m < 2; ++m)
#pragma unroll
        for (int j = 0; j < 4; ++j) part[m][j] = 0.0f;
#pragma unroll
    for (int n = 0; n < 4; ++n) {
        const int cc = wcC + n*16 + lr;
        const float bb = cb1[cc];
        const float cw = cW2v[cc];
#pragma unroll
        for (int m = 0; m < 2; ++m)
#pragma unroll
            for (int j = 0; j < 4; ++j)
                part[m][j] += siluf(acc3[m][n][j] + bb) * cw;
    }
#pragma unroll
    for (int off = 1; off < 16; off <<= 1)
#pragma unroll
        for (int m = 0; m < 2; ++m)
#pragma unroll
            for (int j = 0; j < 4; ++j)
                part[m][j] += __shfl_xor(part[m][j], off, 64);
    if (lr == 0) {
#pragma unroll
        for (int m = 0; m < 2; ++m)
#pragma unroll
            for (int j = 0; j < 4; ++j)
                wred[wave & 1][wr + m*16 + g0*4 + j] = part[m][j];
    }
    __syncthreads();
    if (t < EB) wvout[row0 + t] = wred[0][t] + wred[1][t] + cb2v[0];
    // coalesced msg16 store from Hs (unswizzle on the fly): 8 x uint4 per thread
#pragma unroll
    for (int k = 0; k < 8; ++k) {
        const int off = (t + k*256) * 16;     // byte offset in Hs (32KB)
        const int row = off >> 9;
        const int cg = ((off >> 4) & 31) ^ (row & 7);
        uint4 v = *reinterpret_cast<const uint4*>(R0 + off);
        *reinterpret_cast<uint4*>(msg16 + (size_t)(row0 + row)*256 + cg*8) = v;
    }
}

// Fused node chain: t1 = silu([nf16|aggr16] @ nW1 + nb1); nf += t1 @ nW2 + nb2.
__global__ __launch_bounds__(256) void nodefused(
        const ushort* __restrict__ nf16, const ushort* __restrict__ aggr16,
        const ushort* __restrict__ nW1t,   // [256][384]
        const ushort* __restrict__ nW2t,   // [128][256]
        const float* __restrict__ nb1, const float* __restrict__ nb2,
        float* __restrict__ nf, ushort* __restrict__ nf16out) {
    __shared__ alignas(16) ushort Ab[12*2048];     // 48KB: 12 chunks of [64][32]
    __shared__ alignas(16) char HsB[32768];        // t1 tile, swizzled
    __shared__ alignas(16) ushort Bs[2][256*32];   // 32KB weight dbuf
    const int t = threadIdx.x, wave = t >> 6, lane = t & 63;
    const int r0 = blockIdx.x*64;
    const int wr = (wave >> 1)*32;
    const int wcB = (wave & 1)*128;
    const int lr = lane & 15, g0 = lane >> 4;

#pragma unroll
    for (int c = 0; c < 3; ++c) {
        const int ks = wave*3 + c;
#pragma unroll
        for (int q = 0; q < 4; ++q) {
            const int r = q*16 + (lane >> 2);
            const int g = (lane & 3) ^ ((r >> 1) & 3);
            const int col = ks*32 + g*8;
            const ushort* gp = (col < NDIM)
                ? nf16 + (size_t)(r0 + r)*NDIM + col
                : aggr16 + (size_t)(r0 + r)*HDIM + (col - NDIM);
            gl_lds(gp, Ab + ks*2048 + q*16*32);
        }
    }
    const ushort* baseW1[4];
    uint ldsBq[4];
#pragma unroll
    for (int q = 0; q < 4; ++q) {
        const int rowb = wave*64 + q*16 + (lane >> 2);
        const int gB = (lane & 3) ^ ((rowb >> 1) & 3);
        baseW1[q] = nW1t + (size_t)rowb*384 + gB*8;
        ldsBq[q] = (uint)(wave*64 + q*16)*32;
    }
    const ushort* baseW2[2];
    uint ldsCq[2];
#pragma unroll
    for (int q = 0; q < 2; ++q) {
        const int rowb = wave*32 + q*16 + (lane >> 2);
        const int gB = (lane & 3) ^ ((rowb >> 1) & 3);
        baseW2[q] = nW2t + (size_t)rowb*256 + gB*8;
        ldsCq[q] = (uint)(wave*32 + q*16)*32;
    }
#pragma unroll
    for (int q = 0; q < 4; ++q)
        gl_lds(baseW1[q], &Bs[0][ldsBq[q]]);
    asm volatile("s_waitcnt vmcnt(0)" ::: "memory");
    __builtin_amdgcn_s_barrier();

    f32x4 acc[2][8];
#pragma unroll
    for (int m = 0; m < 2; ++m)
#pragma unroll
        for (int n = 0; n < 8; ++n) acc[m][n] = (f32x4){0.f,0.f,0.f,0.f};
    int cur = 0;
#pragma unroll
    for (int it = 0; it < 12; ++it) {
        if (it + 1 < 12) {
            const int k0 = (it + 1)*32;
#pragma unroll
            for (int q = 0; q < 4; ++q)
                gl_lds(baseW1[q] + k0, &Bs[cur^1][ldsBq[q]]);
            asm volatile("s_waitcnt vmcnt(4)" ::: "memory");
        } else {
            asm volatile("s_waitcnt vmcnt(0)" ::: "memory");
        }
        __builtin_amdgcn_s_barrier();
        bf16x8 af[2], bfr[8];
#pragma unroll
        for (int m = 0; m < 2; ++m) {
            const int rA = wr + m*16 + lr;
            af[m] = *reinterpret_cast<const bf16x8*>(&Ab[it*2048 + rA*32 + ((g0 ^ ((rA>>1)&3)))*8]);
        }
#pragma unroll
        for (int n = 0; n < 8; ++n) {
            const int rB = wcB + n*16 + lr;
            bfr[n] = *reinterpret_cast<const bf16x8*>(&Bs[cur][rB*32 + ((g0 ^ ((rB>>1)&3)))*8]);
        }
        __builtin_amdgcn_s_setprio(1);
#pragma unroll
        for (int m = 0; m < 2; ++m)
#pragma unroll
            for (int n = 0; n < 8; ++n)
                acc[m][n] = __builtin_amdgcn_mfma_f32_16x16x32_bf16(af[m], bfr[n], acc[m][n], 0, 0, 0);
        __builtin_amdgcn_s_setprio(0);
        __builtin_amdgcn_s_barrier();
        cur ^= 1;
    }
#pragma unroll
    for (int q = 0; q < 2; ++q)
        gl_lds(baseW2[q], &Bs[0][ldsCq[q]]);
#pragma unroll
    for (int n = 0; n < 8; ++n) {
        const int cc = wcB + n*16 + lr;
        const float b1 = nb1[cc];
#pragma unroll
        for (int m = 0; m < 2; ++m) {
#pragma unroll
            for (int j = 0; j < 4; ++j) {
                const int rr = wr + m*16 + g0*4 + j;
                *(ushort*)(HsB + rr*512 + ((cc*2) ^ ((rr&7)<<4))) = f2b(siluf(acc[m][n][j] + b1));
            }
        }
    }
    __syncthreads();

    const int wcC = (wave & 1)*64;
    f32x4 acc3[2][4];
#pragma unroll
    for (int m = 0; m < 2; ++m)
#pragma unroll
        for (int n = 0; n < 4; ++n) acc3[m][n] = (f32x4){0.f,0.f,0.f,0.f};
    cur = 0;
#pragma unroll
    for (int it = 0; it < 8; ++it) {
        if (it + 1 < 8) {
            const int k0 = (it + 1)*32;
#pragma unroll
            for (int q = 0; q < 2; ++q)
                gl_lds(baseW2[q] + k0, &Bs[cur^1][ldsCq[q]]);
            asm volatile("s_waitcnt vmcnt(2)" ::: "memory");
        } else {
            asm volatile("s_waitcnt vmcnt(0)" ::: "memory");
        }
        __builtin_amdgcn_s_barrier();
        bf16x8 af[2], bfr[4];
#pragma unroll
        for (int m = 0; m < 2; ++m) {
            const int rA = wr + m*16 + lr;
            const int kc = it*4 + g0;
            af[m] = *reinterpret_cast<const bf16x8*>(HsB + rA*512 + ((kc*16) ^ ((rA&7)<<4)));
        }
#pragma unroll
        for (int n = 0; n < 4; ++n) {
            const int rB = wcC + n*16 + lr;
            bfr[n] = *reinterpret_cast<const bf16x8*>(&Bs[cur][rB*32 + ((g0 ^ ((rB>>1)&3)))*8]);
        }
        __builtin_amdgcn_s_setprio(1);
#pragma unroll
        for (int m = 0; m < 2; ++m)
#pragma unroll
            for (int n = 0; n < 4; ++n)
                acc3[m][n] = __builtin_amdgcn_mfma_f32_16x16x32_bf16(af[m], bfr[n], acc3[m][n], 0, 0, 0);
        __builtin_amdgcn_s_setprio(0);
        __builtin_amdgcn_s_barrier();
        cur ^= 1;
    }
#pragma unroll
    for (int n = 0; n < 4; ++n) {
        const int cc = wcC + n*16 + lr;
        const float b2 = nb2[cc];
#pragma unroll
        for (int m = 0; m < 2; ++m) {
#pragma unroll
            for (int j = 0; j < 4; ++j) {
                const int rr = r0 + wr + m*16 + g0*4 + j;
                float x = acc3[m][n][j] + b2 + nf[(size_t)rr*NDIM + cc];
                nf[(size_t)rr*NDIM + cc] = x;
                nf16out[(size_t)rr*NDIM + cc] = f2b(x);
            }
        }
    }
}

// merged per-node kernel: aggr (segment-sum of msg) + coords update. One wave per node.
__global__ void node_kernel(const ushort* __restrict__ msg16, const float* __restrict__ cold,
                            const float* __restrict__ wv, const int* __restrict__ ccnt,
                            const int* __restrict__ cedg,
                            ushort* __restrict__ aggr16, float* __restrict__ cnew) {
    __shared__ int se[4][64];
    const int w = threadIdx.x >> 6, lane = threadIdx.x & 63;
    const int j = blockIdx.x*4 + w;
    const int cnt = min(ccnt[j], MAXDEG);
    se[w][lane] = (lane < cnt) ? cedg[(size_t)j*MAXDEG + lane] : 0;
    __syncthreads();
    const int c4 = lane*4;
    float s0 = 0, s1 = 0, s2 = 0, s3 = 0;
    const int lim = min(cnt, 64);
    for (int q = 0; q < lim; ++q) {
        const int e = se[w][q];
        ushort4 v = *reinterpret_cast<const ushort4*>(&msg16[(size_t)e*HDIM + c4]);
        s0 += b2f(v.x); s1 += b2f(v.y); s2 += b2f(v.z); s3 += b2f(v.w);
    }
    for (int q = 64; q < cnt; ++q) {
        const int e = cedg[(size_t)j*MAXDEG + q];
        ushort4 v = *reinterpret_cast<const ushort4*>(&msg16[(size_t)e*HDIM + c4]);
        s0 += b2f(v.x); s1 += b2f(v.y); s2 += b2f(v.z); s3 += b2f(v.w);
    }
    ushort4 o; o.x = f2b(s0); o.y = f2b(s1); o.z = f2b(s2); o.w = f2b(s3);
    *reinterpret_cast<ushort4*>(&aggr16[(size_t)j*HDIM + c4]) = o;
    const float jx = cold[j*3], jy = cold[j*3+1], jz = cold[j*3+2];
    float dx = 0, dy = 0, dz = 0;
    for (int q = lane; q < cnt; q += 64) {
        const int e = (q < 64) ? se[w][q] : cedg[(size_t)j*MAXDEG + q];
        const int si = e / KN;
        const float ax = cold[si*3]   - jx;
        const float ay = cold[si*3+1] - jy;
        const float az = cold[si*3+2] - jz;
        const float inv = wv[e] / (sqrtf(ax*ax + ay*ay + az*az) + 1e-8f);
        dx += inv*ax; dy += inv*ay; dz += inv*az;
    }
    for (int off = 32; off > 0; off >>= 1) {
        dx += __shfl_xor(dx, off, 64);
        dy += __shfl_xor(dy, off, 64);
        dz += __shfl_xor(dz, off, 64);
    }
    if (lane == 0) {
        cnew[j*3]   = jx + dx;
        cnew[j*3+1] = jy + dy;
        cnew[j*3+2] = jz + dz;
    }
}

__global__ void copyout_kernel(const float* __restrict__ nf, const float* __restrict__ coords,
                               float* __restrict__ out) {
    int idx = blockIdx.x*256 + threadIdx.x;
    if (idx < NA*NDIM) out[idx] = nf[idx];
    else if (idx < NA*NDIM + NA*3) out[idx] = coords[idx - NA*NDIM];
}

extern "C" void kernel_launch(void* const* d_in, const int* in_sizes, int n_in,
                              void* d_out, int out_size, void* d_ws, size_t ws_size,
                              hipStream_t stream) {
    const int*   atom_types = (const int*)  d_in[0];
    const float* frac       = (const float*)d_in[1];
    const float* lengths    = (const float*)d_in[2];
    const float* angles     = (const float*)d_in[3];
    const float* timesteps  = (const float*)d_in[4];
    const float* emb        = (const float*)d_in[5];
    const float* tW         = (const float*)d_in[6];
    const float* tb         = (const float*)d_in[7];
    const float* eW1        = (const float*)d_in[8];
    const float* eb1        = (const float*)d_in[9];
    const float* eW2        = (const float*)d_in[10];
    const float* eb2        = (const float*)d_in[11];
    const float* nW1        = (const float*)d_in[12];
    const float* nb1        = (const float*)d_in[13];
    const float* nW2        = (const float*)d_in[14];
    const float* nb2        = (const float*)d_in[15];
    const float* cW1        = (const float*)d_in[16];
    const float* cb1        = (const float*)d_in[17];
    const float* cW2        = (const float*)d_in[18];
    const float* cb2        = (const float*)d_in[19];

    char* p = (char*)d_ws;
    auto alloc = [&](size_t bytes) { char* q = p; p += (bytes + 255) & ~(size_t)255; return q; };
    float*  sv    = (float*) alloc(81*4);
    float*  c0    = (float*) alloc((size_t)NA*3*4);
    float*  c1    = (float*) alloc((size_t)NA*3*4);
    float*  cxg   = (float*) alloc((size_t)NA*4);
    float*  cyg   = (float*) alloc((size_t)NA*4);
    float*  czg   = (float*) alloc((size_t)NA*4);
    float*  nf    = (float*) alloc((size_t)NA*NDIM*4);
    int*    dstl  = (int*)   alloc((size_t)NE*4);
    ushort* rbf16 = (ushort*)alloc((size_t)NE*EDIM*2);
    int*    ccnt  = (int*)   alloc((size_t)NA*4);
    int*    cedg  = (int*)   alloc((size_t)NA*MAXDEG*4);
    ushort* aggr16= (ushort*)alloc((size_t)NA*HDIM*2);
    float*  wv    = (float*) alloc((size_t)NE*4);
    ushort* nf16  = (ushort*)alloc((size_t)NA*NDIM*2);
    ushort* msg16 = (ushort*)alloc((size_t)NE*HDIM*2);
    ushort* eW1t  = (ushort*)alloc((size_t)NLAYER*(2*NDIM+EDIM)*HDIM*2);
    ushort* eW2t  = (ushort*)alloc((size_t)NLAYER*HDIM*HDIM*2);
    ushort* cW1t  = (ushort*)alloc((size_t)NLAYER*(HDIM/2)*HDIM*2);
    ushort* nW1t  = (ushort*)alloc((size_t)NLAYER*(NDIM+HDIM)*HDIM*2);
    ushort* nW2t  = (ushort*)alloc((size_t)NLAYER*HDIM*NDIM*2);

    setup_kernel<<<8, 256, 0, stream>>>(frac, lengths, angles, c0, cxg, cyg, czg, sv, ccnt);
    knn_kernel<<<NA, 64, 0, stream>>>(cxg, cyg, czg, lengths, angles, sv,
                                      dstl, rbf16, ccnt, cedg);
    csort_kernel<<<NA/4, 256, 0, stream>>>(ccnt, cedg);
    nf_init_kernel<<<NA, 128, 0, stream>>>(atom_types, timesteps, emb, tW, tb, nf, nf16);
    wprep_all<<<304, 256, 0, stream>>>(eW1, eW2, cW1, nW1, nW2,
                                       eW1t, eW2t, cW1t, nW1t, nW2t);

    float* cin = c0; float* cout = c1;
    for (int l = 0; l < NLAYER; ++l) {
        const float* eb1l = eb1 + (size_t)l*HDIM;
        const float* eb2l = eb2 + (size_t)l*HDIM;
        const float* nb1l = nb1 + (size_t)l*HDIM;
        const float* nb2l = nb2 + (size_t)l*NDIM;
        const float* cb1l = cb1 + (size_t)l*(HDIM/2);
        const float* cW2l = cW2 + (size_t)l*(HDIM/2);
        const float* cb2l = cb2 + (size_t)l;

        // fused edge chain: h1 -> msg -> wv
        edge_fused<<<NE/EB, 256, 0, stream>>>(
            nf16, dstl, rbf16,
            eW1t + (size_t)l*(2*NDIM+EDIM)*HDIM, eW2t + (size_t)l*HDIM*HDIM,
            cW1t + (size_t)l*(HDIM/2)*HDIM,
            eb1l, eb2l, cb1l, cW2l, cb2l, msg16, wv);
        // aggr + coords (merged)
        node_kernel<<<NA/4, 256, 0, stream>>>(msg16, cin, wv, ccnt, cedg, aggr16, cout);
        // fused node chain: t1 -> nf update
        nodefused<<<NA/64, 256, 0, stream>>>(
            nf16, aggr16, nW1t + (size_t)l*(NDIM+HDIM)*HDIM, nW2t + (size_t)l*HDIM*NDIM,
            nb1l, nb2l, nf, nf16);
        float* tmp = cin; cin = cout; cout = tmp;
    }
    copyout_kernel<<<(NA*NDIM + NA*3)/256, 256, 0, stream>>>(nf, cin, (float*)d_out);
}